// Round 10
// baseline (1425.317 us; speedup 1.0000x reference)
//
#include <hip/hip_runtime.h>
#include <hip/hip_bf16.h>

#define L_N 2
#define D_ 2048
#define H_ 16
#define DH_ 128
#define DFF_ 5504
#define B_ 4
#define S_ 1000
#define C_ 7
#define T_ 45
#define M_ 4000   // B_*S_

typedef short bf16x8 __attribute__((ext_vector_type(8)));
typedef float f32x4 __attribute__((ext_vector_type(4)));

__constant__ float NF4_TAB[16] = {
  -1.0f, -0.6961928009986877f, -0.5250730514526367f, -0.39491748809814453f,
  -0.28444138169288635f, -0.18477343022823334f, -0.09105003625154495f, 0.0f,
  0.07958029955625534f, 0.16093020141124725f, 0.24611230194568634f,
  0.3379152417182922f, 0.44070982933044434f, 0.5626170039176941f,
  0.7229568362236023f, 1.0f };

__device__ __forceinline__ unsigned short f2bf(float f) {
  unsigned int u = __float_as_uint(f);
  u += 0x7fffu + ((u >> 16) & 1u);          // RNE
  return (unsigned short)(u >> 16);
}
__device__ __forceinline__ float bf2f(unsigned short u) {
  return __uint_as_float(((unsigned int)u) << 16);
}
__device__ __forceinline__ f32x4 zero4() { f32x4 z; z[0]=0.f; z[1]=0.f; z[2]=0.f; z[3]=0.f; return z; }
__device__ __forceinline__ f32x4 mfma16(bf16x8 a, bf16x8 b, f32x4 c) {
  return __builtin_amdgcn_mfma_f32_16x16x32_bf16(a, b, c, 0, 0, 0);
}

typedef __attribute__((address_space(3))) unsigned int lds_u32;
typedef const __attribute__((address_space(1))) unsigned int glb_u32;
__device__ __forceinline__ void gload16(const void* g, void* l) {
  __builtin_amdgcn_global_load_lds((glb_u32*)g, (lds_u32*)l, 16, 0, 0);
}

// ---------------- rope tables ----------------
__global__ void rope_tables(float* __restrict__ cosT, float* __restrict__ sinT) {
  int s = blockIdx.x, d = threadIdx.x;   // 128 threads
  int j = d & 63;
  float inv = expf(-(float)j * (9.210340371976184f / 64.f)); // 10000^(-j/64)
  float ang = (float)s * inv;
  cosT[s * DH_ + d] = cosf(ang);
  sinT[s * DH_ + d] = sinf(ang);
}

// ---------------- embedding gather ----------------
__global__ __launch_bounds__(256) void embed_gather(const int* __restrict__ tok,
    const float* __restrict__ emb, float* __restrict__ h) {
  int row = blockIdx.x;                 // 0..3999  (b*S+s)
  int tk = tok[row];
  const float4* src = reinterpret_cast<const float4*>(emb + (size_t)tk * D_);
  float4* dst = reinterpret_cast<float4*>(h + (size_t)row * D_);
  dst[threadIdx.x] = src[threadIdx.x];
  dst[threadIdx.x + 256] = src[threadIdx.x + 256];
}

// ---------------- rmsnorm (+optional k-split merge): fp32 in -> bf16 out ----------------
__global__ __launch_bounds__(256) void rmsnorm_k(float* __restrict__ h,
    const float* __restrict__ add, const float* __restrict__ w,
    unsigned short* __restrict__ out) {
  const int row = blockIdx.x, t = threadIdx.x;
  float* hp = h + (size_t)row * D_;
  float4 a = *reinterpret_cast<const float4*>(&hp[t * 8]);
  float4 b = *reinterpret_cast<const float4*>(&hp[t * 8 + 4]);
  if (add) {
    const float* ap = add + (size_t)row * D_;
    float4 da = *reinterpret_cast<const float4*>(&ap[t * 8]);
    float4 db = *reinterpret_cast<const float4*>(&ap[t * 8 + 4]);
    a.x += da.x; a.y += da.y; a.z += da.z; a.w += da.w;
    b.x += db.x; b.y += db.y; b.z += db.z; b.w += db.w;
    *reinterpret_cast<float4*>(&hp[t * 8]) = a;
    *reinterpret_cast<float4*>(&hp[t * 8 + 4]) = b;
  }
  float ss = a.x*a.x + a.y*a.y + a.z*a.z + a.w*a.w
           + b.x*b.x + b.y*b.y + b.z*b.z + b.w*b.w;
#pragma unroll
  for (int m = 1; m < 64; m <<= 1) ss += __shfl_xor(ss, m);
  __shared__ float red[4];
  if ((t & 63) == 0) red[t >> 6] = ss;
  __syncthreads();
  float tot = red[0] + red[1] + red[2] + red[3];
  float rs = rsqrtf(tot * (1.0f / D_) + 1e-5f);
  float4 wa = *reinterpret_cast<const float4*>(&w[t * 8]);
  float4 wb = *reinterpret_cast<const float4*>(&w[t * 8 + 4]);
  unsigned r0 = (unsigned)f2bf(a.x*rs*wa.x) | ((unsigned)f2bf(a.y*rs*wa.y) << 16);
  unsigned r1 = (unsigned)f2bf(a.z*rs*wa.z) | ((unsigned)f2bf(a.w*rs*wa.w) << 16);
  unsigned r2 = (unsigned)f2bf(b.x*rs*wb.x) | ((unsigned)f2bf(b.y*rs*wb.y) << 16);
  unsigned r3 = (unsigned)f2bf(b.z*rs*wb.z) | ((unsigned)f2bf(b.w*rs*wb.w) << 16);
  int4 ov; ov.x = (int)r0; ov.y = (int)r1; ov.z = (int)r2; ov.w = (int)r3;
  *reinterpret_cast<int4*>(&out[(size_t)row * D_ + t * 8]) = ov;
}

// ---------------- batched NF4 dequant: up to 4 matrices, uniform K ----------------
struct DqJob { const int* idx; const float* sc; unsigned short* out; };
struct DqBatch { DqJob j[4]; };

__global__ __launch_bounds__(256) void dequant_batch(DqBatch bt, int K) {
  __shared__ float nf4[16];
  const int t = threadIdx.x;
  if (t < 16) nf4[t] = NF4_TAB[t];
  __syncthreads();
  const DqJob jb = bt.j[blockIdx.z];
  const int row = blockIdx.y;
  const int k0 = blockIdx.x * 2048 + t * 8;
  if (k0 >= K) return;
  const size_t base = (size_t)row * K + k0;
  int4 a = *reinterpret_cast<const int4*>(&jb.idx[base]);
  int4 b = *reinterpret_cast<const int4*>(&jb.idx[base + 4]);
  float s = jb.sc[(size_t)row * (K >> 6) + (k0 >> 6)];
  unsigned r0 = (unsigned)f2bf(nf4[a.x & 15] * s) | ((unsigned)f2bf(nf4[a.y & 15] * s) << 16);
  unsigned r1 = (unsigned)f2bf(nf4[a.z & 15] * s) | ((unsigned)f2bf(nf4[a.w & 15] * s) << 16);
  unsigned r2 = (unsigned)f2bf(nf4[b.x & 15] * s) | ((unsigned)f2bf(nf4[b.y & 15] * s) << 16);
  unsigned r3 = (unsigned)f2bf(nf4[b.z & 15] * s) | ((unsigned)f2bf(nf4[b.w & 15] * s) << 16);
  int4 ov; ov.x = (int)r0; ov.y = (int)r1; ov.z = (int)r2; ov.w = (int)r3;
  *reinterpret_cast<int4*>(&jb.out[base]) = ov;
}

// ======== PIPELINED bf16 GEMM: dbuf + counted vmcnt + raw barriers (T3-min/T4) ========
// MODE 0: z picks (Bw,outp) / (Bw2,outp2); out bf16 [M][N]   (co-scheduled pair)
// MODE 1: out bf16 qkv layout [which][B][H][S][DH]
// Sync ledger: stage(kt+1)->buf[cur^1]; vmcnt(8) retires stage(kt)'s 8 oldest loads;
// raw barrier (no drain) makes buf[cur] visible; trailing barrier protects buf[cur]
// from next iter's overwrite (its ds_reads were consumed before MFMA issue).
template<int MODE>
__global__ __launch_bounds__(256, 4) void gemm_pipe(
    const unsigned short* __restrict__ A,
    const unsigned short* __restrict__ Bw,
    const unsigned short* __restrict__ Bw2,
    int Mdim, int N, int K,
    void* outp, void* outp2) {
  __shared__ unsigned short A_lds[2][128 * 64];   // 2 x 16 KiB, XOR-swizzled
  __shared__ unsigned short B_lds[2][128 * 64];
  const int t = threadIdx.x;
  const int lane = t & 63, wid = t >> 6;
  const int z = blockIdx.z;

  const unsigned short* Bsrc = (MODE == 0 && z) ? Bw2 : Bw;
  void* osel = (MODE == 0 && z) ? outp2 : outp;

  // XCD-banded m-grouped mapping (my == 32 == 8 xcd * 4 for all launches)
  const int bid = blockIdx.x;
  const int xcd = bid & 7, l = bid >> 3;
  const int m_blk = xcd * 4 + (l & 3);
  const int n_blk = l >> 2;
  const int n0 = n_blk * 128;
  const int m0 = m_blk * 128;

  const int wm = (wid >> 1) * 64, wn = (wid & 1) * 64;
  const int lr = lane & 15, lg = lane >> 4;
  const int lrow = lane >> 3;
  const int lslot = (((lane & 7) ^ lrow) << 4);
  const int rswz = (lr & 7) << 4;

  f32x4 acc[4][4];
#pragma unroll
  for (int i = 0; i < 4; ++i)
#pragma unroll
    for (int j = 0; j < 4; ++j) acc[i][j] = zero4();

  const int kT = K >> 6;
  const size_t rowb = (size_t)(K * 2);

  auto stage = [&](int kt, int b) {
#pragma unroll
    for (int c0 = 0; c0 < 4; ++c0) {
      const int c = wid + 4 * c0;
      int gr = m0 + c * 8 + lrow;
      gr = gr < Mdim ? gr : Mdim - 1;
      gload16((const char*)A + (size_t)gr * rowb + kt * 128 + lslot,
              (char*)&A_lds[b][0] + c * 1024);
      const int nr = n0 + c * 8 + lrow;
      gload16((const char*)Bsrc + (size_t)nr * rowb + kt * 128 + lslot,
              (char*)&B_lds[b][0] + c * 1024);
    }
  };

  stage(0, 0);
  for (int kt = 0; kt < kT; ++kt) {
    const int cur = kt & 1;
    if (kt + 1 < kT) {
      stage(kt + 1, cur ^ 1);                         // 8 loads stay in flight
      asm volatile("s_waitcnt vmcnt(8)" ::: "memory"); // retire stage(kt) only
    } else {
      asm volatile("s_waitcnt vmcnt(0)" ::: "memory");
    }
    __builtin_amdgcn_s_barrier();
    __builtin_amdgcn_sched_barrier(0);                // fence ds_reads below barrier
#pragma unroll
    for (int ks = 0; ks < 2; ++ks) {
      bf16x8 af[4], bfr[4];
      const int cb = (ks * 64 + lg * 16) ^ rswz;
#pragma unroll
      for (int i = 0; i < 4; ++i) {
        af[i]  = *reinterpret_cast<const bf16x8*>(
                   (const char*)&A_lds[cur][0] + (wm + i * 16 + lr) * 128 + cb);
        bfr[i] = *reinterpret_cast<const bf16x8*>(
                   (const char*)&B_lds[cur][0] + (wn + i * 16 + lr) * 128 + cb);
      }
      __builtin_amdgcn_s_setprio(1);
#pragma unroll
      for (int mi = 0; mi < 4; ++mi)
#pragma unroll
        for (int ni = 0; ni < 4; ++ni)
          acc[mi][ni] = mfma16(af[mi], bfr[ni], acc[mi][ni]);
      __builtin_amdgcn_s_setprio(0);
    }
    __builtin_amdgcn_s_barrier();
  }

#pragma unroll
  for (int mi = 0; mi < 4; ++mi) {
#pragma unroll
    for (int r = 0; r < 4; ++r) {
      int gm = m0 + wm + mi * 16 + lg * 4 + r;
      if (gm >= Mdim) continue;
#pragma unroll
      for (int ni = 0; ni < 4; ++ni) {
        int gn = n0 + wn + ni * 16 + lr;
        float v = acc[mi][ni][r];
        if (MODE == 0) {
          ((unsigned short*)osel)[(size_t)gm * N + gn] = f2bf(v);
        } else {
          const int which = gn >> 11;
          const int hh = (gn >> 7) & 15, dd = gn & 127;
          const int b = gm / S_, s = gm - b * S_;
          ((unsigned short*)outp)[
            (((size_t)which * (B_ * H_) + b * H_ + hh) * S_ + s) * DH_ + dd] = f2bf(v);
        }
      }
    }
  }
}

// ---------------- bf16 GEMM (single-buffer 2-phase) — k-split control path --------
// MODE 3: fp32 k-split: z==0 (kt in [0,ksplit)) -> outp += acc;
//                       z==1 (kt in [ksplit,kT)) -> dscr = acc
template<int MODE>
__global__ __launch_bounds__(256, 4) void gemm_bf16(
    const unsigned short* __restrict__ A,
    const unsigned short* __restrict__ Bw,
    const unsigned short* __restrict__ Bw2,
    int Mdim, int N, int K, int nx, int ksplit,
    void* outp, void* outp2, float* dscr) {
  __shared__ unsigned short A_lds[128 * 64];   // XOR-swizzled rows, 16 KiB
  __shared__ unsigned short B_lds[128 * 64];
  const int t = threadIdx.x;
  const int lane = t & 63, wid = t >> 6;
  const int z = blockIdx.z;

  const unsigned short* Bsrc = (MODE == 0 && z) ? Bw2 : Bw;
  void* osel = (MODE == 0 && z) ? outp2 : outp;

  const int bid = blockIdx.x;
  const int xcd = bid & 7, l = bid >> 3;
  const int m_blk = xcd * 4 + (l & 3);
  const int n_blk = l >> 2;
  const int n0 = n_blk * 128;
  const int m0 = m_blk * 128;

  const int wm = (wid >> 1) * 64, wn = (wid & 1) * 64;
  const int lr = lane & 15, lg = lane >> 4;
  const int lrow = lane >> 3;
  const int lslot = (((lane & 7) ^ lrow) << 4);
  const int rswz = (lr & 7) << 4;

  f32x4 acc[4][4];
#pragma unroll
  for (int i = 0; i < 4; ++i)
#pragma unroll
    for (int j = 0; j < 4; ++j) acc[i][j] = zero4();

  const int kT = K >> 6;
  const int ktlo = (MODE == 3) ? (z ? ksplit : 0) : 0;
  const int kthi = (MODE == 3) ? (z ? kT : ksplit) : kT;
  const size_t rowb = (size_t)(K * 2);

  for (int kt = ktlo; kt < kthi; ++kt) {
#pragma unroll
    for (int c0 = 0; c0 < 4; ++c0) {
      const int c = wid + 4 * c0;
      int gr = m0 + c * 8 + lrow;
      gr = gr < Mdim ? gr : Mdim - 1;
      gload16((const char*)A + (size_t)gr * rowb + kt * 128 + lslot,
              (char*)&A_lds[0] + c * 1024);
      const int nr = n0 + c * 8 + lrow;
      gload16((const char*)Bsrc + (size_t)nr * rowb + kt * 128 + lslot,
              (char*)&B_lds[0] + c * 1024);
    }
    __syncthreads();
#pragma unroll
    for (int ks = 0; ks < 2; ++ks) {
      bf16x8 af[4], bfr[4];
      const int cb = (ks * 64 + lg * 16) ^ rswz;
#pragma unroll
      for (int i = 0; i < 4; ++i) {
        af[i]  = *reinterpret_cast<const bf16x8*>(
                   (const char*)&A_lds[0] + (wm + i * 16 + lr) * 128 + cb);
        bfr[i] = *reinterpret_cast<const bf16x8*>(
                   (const char*)&B_lds[0] + (wn + i * 16 + lr) * 128 + cb);
      }
      __builtin_amdgcn_s_setprio(1);
#pragma unroll
      for (int mi = 0; mi < 4; ++mi)
#pragma unroll
        for (int ni = 0; ni < 4; ++ni)
          acc[mi][ni] = mfma16(af[mi], bfr[ni], acc[mi][ni]);
      __builtin_amdgcn_s_setprio(0);
    }
    __syncthreads();
  }

#pragma unroll
  for (int mi = 0; mi < 4; ++mi) {
#pragma unroll
    for (int r = 0; r < 4; ++r) {
      int gm = m0 + wm + mi * 16 + lg * 4 + r;
      if (gm >= Mdim) continue;
#pragma unroll
      for (int ni = 0; ni < 4; ++ni) {
        int gn = n0 + wn + ni * 16 + lr;
        float v = acc[mi][ni][r];
        if (MODE == 0) {
          ((unsigned short*)osel)[(size_t)gm * N + gn] = f2bf(v);
        } else if (MODE == 1) {
          const int which = gn >> 11;
          const int hh = (gn >> 7) & 15, dd = gn & 127;
          const int b = gm / S_, s = gm - b * S_;
          ((unsigned short*)outp)[
            (((size_t)which * (B_ * H_) + b * H_ + hh) * S_ + s) * DH_ + dd] = f2bf(v);
        } else {
          if (z == 0) ((float*)outp)[(size_t)gm * N + gn] += v;
          else        dscr[(size_t)gm * N + gn] = v;
        }
      }
    }
  }
}

// ---------------- silu-mul: g = silu(g) * u (elementwise, bf16) ----------------
__global__ __launch_bounds__(256) void silu_mul(unsigned short* __restrict__ g,
    const unsigned short* __restrict__ u) {
  const size_t i = ((size_t)blockIdx.x * 256 + threadIdx.x) * 8;
  int4 gv = *reinterpret_cast<const int4*>(&g[i]);
  int4 uv = *reinterpret_cast<const int4*>(&u[i]);
  const unsigned* gp = reinterpret_cast<const unsigned*>(&gv);
  const unsigned* up = reinterpret_cast<const unsigned*>(&uv);
  unsigned ov[4];
#pragma unroll
  for (int j = 0; j < 4; ++j) {
    float g0 = bf2f(gp[j] & 0xffffu), g1 = bf2f(gp[j] >> 16);
    float u0 = bf2f(up[j] & 0xffffu), u1 = bf2f(up[j] >> 16);
    float s0 = g0 / (1.f + __expf(-g0)) * u0;
    float s1 = g1 / (1.f + __expf(-g1)) * u1;
    ov[j] = (unsigned)f2bf(s0) | ((unsigned)f2bf(s1) << 16);
  }
  int4 o; o.x = (int)ov[0]; o.y = (int)ov[1]; o.z = (int)ov[2]; o.w = (int)ov[3];
  *reinterpret_cast<int4*>(&g[i]) = o;
}

// ---------------- rope apply (in-place, q & k) ----------------
__global__ __launch_bounds__(256) void rope_apply(unsigned short* __restrict__ qb,
    unsigned short* __restrict__ kb, const float* __restrict__ cosT,
    const float* __restrict__ sinT) {
  size_t i = (size_t)blockIdx.x * 256 + threadIdx.x;  // B*H*S*64 slots
  int d = (int)(i & 63);
  size_t row = i >> 6;              // (b*H+h)*S + s
  int s = (int)(row % S_);
  size_t base = row * DH_;
  float c = cosT[s * DH_ + d], sn = sinT[s * DH_ + d];
  float q0 = bf2f(qb[base + d]), q1 = bf2f(qb[base + d + 64]);
  qb[base + d]      = f2bf(q0 * c - q1 * sn);
  qb[base + d + 64] = f2bf(q1 * c + q0 * sn);
  float k0 = bf2f(kb[base + d]), k1 = bf2f(kb[base + d + 64]);
  kb[base + d]      = f2bf(k0 * c - k1 * sn);
  kb[base + d + 64] = f2bf(k1 * c + k0 * sn);
}

// ---------------- V transpose: vb [b][h][s][128] -> vt [bh][128][1024] ----------------
__global__ __launch_bounds__(256) void vtrans_k(const unsigned short* __restrict__ vb,
    unsigned short* __restrict__ vt) {
  __shared__ unsigned int tile[64][33];
  const int t = threadIdx.x;
  const int s0 = blockIdx.x * 64, d0 = blockIdx.y * 64, bh = blockIdx.z;
#pragma unroll
  for (int j = 0; j < 2; ++j) {
    int idx = t + 256 * j;
    int s_r = idx >> 3, c8 = (idx & 7) << 3;
    int srow = s0 + s_r; srow = srow < S_ ? srow : S_ - 1;
    int4 v = *reinterpret_cast<const int4*>(&vb[((size_t)bh * S_ + srow) * DH_ + d0 + c8]);
    tile[s_r][(c8 >> 1) + 0] = (unsigned)v.x;
    tile[s_r][(c8 >> 1) + 1] = (unsigned)v.y;
    tile[s_r][(c8 >> 1) + 2] = (unsigned)v.z;
    tile[s_r][(c8 >> 1) + 3] = (unsigned)v.w;
  }
  __syncthreads();
#pragma unroll
  for (int j = 0; j < 2; ++j) {
    int idx = t + 256 * j;
    int d_r = idx >> 3, s8 = (idx & 7) << 3;
    unsigned r[8];
#pragma unroll
    for (int e = 0; e < 8; ++e) {
      unsigned wv = tile[s8 + e][d_r >> 1];
      r[e] = (d_r & 1) ? (wv >> 16) : (wv & 0xffffu);
    }
    int4 ov;
    ov.x = (int)(r[0] | (r[1] << 16));
    ov.y = (int)(r[2] | (r[3] << 16));
    ov.z = (int)(r[4] | (r[5] << 16));
    ov.w = (int)(r[6] | (r[7] << 16));
    *reinterpret_cast<int4*>(&vt[((size_t)(bh * 128 + d0 + d_r)) * 1024 + s0 + s8]) = ov;
  }
}

// ---------------- causal flash attention v2 (swapped-QK, 8 waves, 128 q rows) --------
__global__ __launch_bounds__(512, 4) void attn2_k(const unsigned short* __restrict__ qg,
    const unsigned short* __restrict__ kg, const unsigned short* __restrict__ vtg,
    unsigned short* __restrict__ ctx) {
  __shared__ unsigned short K_lds[64 * 128];
  __shared__ unsigned short VT_lds[128 * 64];
  const int t = threadIdx.x, lane = t & 63, w = t >> 6;
  const int lr = lane & 15, lg = lane >> 4;
  const int bh = blockIdx.x, qt = blockIdx.y;
  const int q0 = qt * 128;
  const int b = bh >> 4, hh = bh & 15;
  const size_t kbase2 = (size_t)bh * S_ * DH_ * 2;   // byte base of this head
  const int q_idx = q0 + w * 16 + lr;
  const int swz = (lr & 7) << 4;

  bf16x8 qf[4];
#pragma unroll
  for (int ks = 0; ks < 4; ++ks) {
    bf16x8 z;
#pragma unroll
    for (int e = 0; e < 8; ++e) z[e] = 0;
    if (q_idx < S_)
      z = *reinterpret_cast<const bf16x8*>(
            (const char*)qg + kbase2 + (size_t)q_idx * 256 + ks * 64 + lg * 16);
    qf[ks] = z;
  }
  float mst = -1e30f, lst = 0.f;
  f32x4 cacc[8];
#pragma unroll
  for (int f = 0; f < 8; ++f) cacc[f] = zero4();

  const int q_hi = (q0 + 127 < S_) ? q0 + 127 : S_ - 1;
  const int nt = q_hi / 64 + 1;
  const int wq_max = q0 + w * 16 + 15;

  for (int kt = 0; kt < nt; ++kt) {
    const int kv0 = kt * 64;
    __syncthreads();
    // stage K [64][128] and VT [128][64], XOR-swizzled source -> linear LDS
#pragma unroll
    for (int j = 0; j < 2; ++j) {
      const int chunk = w + 8 * j;            // 0..15, 1024B each
      int krow = chunk * 4 + (lane >> 4);     // 4 rows x 256B
      int kcolb = (lane & 15) << 4;
      int gr = kv0 + krow; gr = gr < S_ ? gr : S_ - 1;
      gload16((const char*)kg + kbase2 + (size_t)gr * 256 + (kcolb ^ ((krow & 7) << 4)),
              (char*)K_lds + chunk * 1024);
      int vrow = chunk * 8 + (lane >> 3);     // 8 rows x 128B
      int vcolb = (lane & 7) << 4;
      gload16((const char*)vtg + ((size_t)(bh * 128 + vrow) * 1024 + kv0) * 2 + (vcolb ^ ((vrow & 7) << 4)),
              (char*)VT_lds + chunk * 1024);
    }
    __syncthreads();
    if (kv0 > wq_max) continue;               // whole wave masked this tile

    // S^T = K . Q^T  (row = kv, col = q = lr)
    f32x4 sacc[4];
#pragma unroll
    for (int c = 0; c < 4; ++c) sacc[c] = zero4();
#pragma unroll
    for (int ks = 0; ks < 4; ++ks) {
#pragma unroll
      for (int c = 0; c < 4; ++c) {
        bf16x8 kf = *reinterpret_cast<const bf16x8*>(
            &K_lds[(c * 16 + lr) * 128 + (((ks * 64 + lg * 16) ^ swz) >> 1)]);
        sacc[c] = mfma16(kf, qf[ks], sacc[c]);
      }
    }
    // mask + online softmax (per-lane scalar m/l; reduce across lg groups)
    float p[4][4];
    float mx = -1e30f;
#pragma unroll
    for (int c = 0; c < 4; ++c)
#pragma unroll
      for (int r = 0; r < 4; ++r) {
        int kv = kv0 + c * 16 + lg * 4 + r;
        float v = sacc[c][r] * 0.08838834764831845f;   // 1/sqrt(128)
        if (kv > q_idx || kv >= S_) v = -1e30f;
        p[c][r] = v;
        mx = fmaxf(mx, v);
      }
    mx = fmaxf(mx, __shfl_xor(mx, 16));
    mx = fmaxf(mx, __shfl_xor(mx, 32));
    float mn = fmaxf(mst, mx);
    float corr = __expf(mst - mn);
    mst = mn;
    float rs = 0.f;
#pragma unroll
    for (int c = 0; c < 4; ++c)
#pragma unroll
      for (int r = 0; r < 4; ++r) {
        float e = __expf(p[c][r] - mn);
        p[c][r] = e;
        rs += e;
      }
    rs += __shfl_xor(rs, 16);
    rs += __shfl_xor(rs, 32);
    lst = lst * corr + rs;
#pragma unroll
    for (int f = 0; f < 8; ++f)
#pragma unroll
      for (int r = 0; r < 4; ++r) cacc[f][r] *= corr;

    // pack P (bf16 pairs) and redistribute to PV B-operand via shfl
    unsigned pk01[4], pk23[4];
#pragma unroll
    for (int c = 0; c < 4; ++c) {
      pk01[c] = (unsigned)f2bf(p[c][0]) | ((unsigned)f2bf(p[c][1]) << 16);
      pk23[c] = (unsigned)f2bf(p[c][2]) | ((unsigned)f2bf(p[c][3]) << 16);
    }
#pragma unroll
    for (int ks = 0; ks < 2; ++ks) {
      unsigned bu[4];
#pragma unroll
      for (int jj = 0; jj < 4; ++jj) {
        const int srcl = ((lg & 1) * 2 + (jj >> 1)) * 16 + lr;
        unsigned lo = (unsigned)__shfl((int)((jj & 1) ? pk23[2 * ks]     : pk01[2 * ks]),     srcl);
        unsigned hi = (unsigned)__shfl((int)((jj & 1) ? pk23[2 * ks + 1] : pk01[2 * ks + 1]), srcl);
        bu[jj] = (lg >= 2) ? hi : lo;
      }
      union { unsigned u[4]; bf16x8 v; } pb;
      pb.u[0] = bu[0]; pb.u[1] = bu[1]; pb.u[2] = bu[2]; pb.u[3] = bu[3];
#pragma unroll
      for (int f = 0; f < 8; ++f) {
        bf16x8 vtf = *reinterpret_cast<const bf16x8*>(
            &VT_lds[(f * 16 + lr) * 64 + (((ks * 64 + lg * 16) ^ swz) >> 1)]);
        cacc[f] = mfma16(vtf, pb.v, cacc[f]);
      }
    }
  }

  // O^T frag: col = q = lr, row = d = f*16 + lg*4 + r  -> packed 8B stores
  if (q_idx < S_) {
    float inv = 1.f / lst;
    unsigned short* cp = ctx + ((size_t)(b * S_ + q_idx)) * D_ + hh * 128;
#pragma unroll
    for (int f = 0; f < 8; ++f) {
      unsigned lo = (unsigned)f2bf(cacc[f][0] * inv) | ((unsigned)f2bf(cacc[f][1] * inv) << 16);
      unsigned hi = (unsigned)f2bf(cacc[f][2] * inv) | ((unsigned)f2bf(cacc[f][3] * inv) << 16);
      uint2 ov; ov.x = lo; ov.y = hi;
      *reinterpret_cast<uint2*>(cp + f * 16 + lg * 4) = ov;
    }
  }
}

// ---------------- mean pool over sequence ----------------
__global__ __launch_bounds__(256) void meanpool(const unsigned short* __restrict__ xn,
    float* __restrict__ out) {
  int d = blockIdx.x * 256 + threadIdx.x;
  int b = blockIdx.y;
  const unsigned short* p = xn + (size_t)b * S_ * D_ + d;
  float s = 0.f;
  for (int i = 0; i < S_; ++i) s += bf2f(p[(size_t)i * D_]);
  out[(size_t)b * D_ + d] = s * (1.f / S_);
}

// ---------------- series branch: adds into out ----------------
__global__ __launch_bounds__(256) void series_k(const float* __restrict__ x,
    const float* __restrict__ pw, const float* __restrict__ pb, float* out) {
  __shared__ float sm[T_];
  __shared__ float emb[D_];
  __shared__ float red[4];
  int b = blockIdx.x, t = threadIdx.x;
  if (t < T_) {
    float s = 0.f;
    for (int c = 0; c < C_; ++c) s += x[((size_t)b * C_ + c) * T_ + t];
    sm[t] = s * (1.f / C_);
  }
  __syncthreads();
  float ssq = 0.f;
#pragma unroll
  for (int j = 0; j < D_ / 256; ++j) {
    int d = j * 256 + t;
    float e = pb[d];
    for (int tt = 0; tt < T_; ++tt) e += sm[tt] * pw[(size_t)d * T_ + tt];
    emb[d] = e;
    ssq += e * e;
  }
#pragma unroll
  for (int m = 1; m < 64; m <<= 1) ssq += __shfl_xor(ssq, m);
  if ((t & 63) == 0) red[t >> 6] = ssq;
  __syncthreads();
  float tot = red[0] + red[1] + red[2] + red[3];
  float inv = 1.f / fmaxf(sqrtf(tot), 1e-12f);
#pragma unroll
  for (int j = 0; j < D_ / 256; ++j) {
    int d = j * 256 + t;
    out[(size_t)b * D_ + d] += emb[d] * inv;
  }
}

extern "C" void kernel_launch(void* const* d_in, const int* in_sizes, int n_in,
                              void* d_out, int out_size, void* d_ws, size_t ws_size,
                              hipStream_t stream) {
  const float* x      = (const float*)d_in[0];
  const int*   tok    = (const int*)d_in[1];
  const float* embedw = (const float*)d_in[2];
  const int*   wq_idx = (const int*)d_in[3];
  const float* wq_sc  = (const float*)d_in[4];
  const int*   wk_idx = (const int*)d_in[5];
  const float* wk_sc  = (const float*)d_in[6];
  const int*   wv_idx = (const int*)d_in[7];
  const float* wv_sc  = (const float*)d_in[8];
  const int*   wo_idx = (const int*)d_in[9];
  const float* wo_sc  = (const float*)d_in[10];
  const int*   wg_idx = (const int*)d_in[11];
  const float* wg_sc  = (const float*)d_in[12];
  const int*   wu_idx = (const int*)d_in[13];
  const float* wu_sc  = (const float*)d_in[14];
  const int*   wd_idx = (const int*)d_in[15];
  const float* wd_sc  = (const float*)d_in[16];
  const float* ln1    = (const float*)d_in[17];
  const float* ln2    = (const float*)d_in[18];
  const float* lnf    = (const float*)d_in[19];
  const float* projw  = (const float*)d_in[20];
  const float* projb  = (const float*)d_in[21];
  float* out = (float*)d_out;
  (void)in_sizes; (void)n_in; (void)out_size; (void)ws_size;

  char* wsp = (char*)d_ws;
  size_t off = 0;
  auto alloc = [&](size_t bytes) -> void* {
    void* p = wsp + off; off += (bytes + 255) & ~(size_t)255; return p; };
  float* cosT = (float*)alloc((size_t)S_ * DH_ * 4);
  float* sinT = (float*)alloc((size_t)S_ * DH_ * 4);
  float* hbuf = (float*)alloc((size_t)M_ * D_ * 4);
  unsigned short* xn   = (unsigned short*)alloc((size_t)M_ * D_ * 2);
  unsigned short* qkv  = (unsigned short*)alloc((size_t)3 * B_ * H_ * S_ * DH_ * 2); // 49.2MB
  unsigned short* wdeq = (unsigned short*)alloc((size_t)2 * DFF_ * D_ * 2);          // 45.1MB
  unsigned short* vt   = (unsigned short*)alloc((size_t)B_ * H_ * DH_ * 1024 * 2);   // 16.8MB
  void* R = alloc((size_t)M_ * DFF_ * 2);   // 44.1MB, time-shared: dscr (fp32 M*D) / ubuf
  float* dscr = (float*)R;                  // live: O-z1 -> ln2 merge; D-z1 -> next merge
  unsigned short* ubuf = (unsigned short*)R;// live: G/U launch -> silu_mul (disjoint)
  const size_t NH = (size_t)B_ * H_ * S_ * DH_;
  unsigned short* qb = qkv, *kb = qkv + NH, *vb = qkv + 2 * NH;
  unsigned short* ctx  = xn;     // alias: xn dead during attention
  unsigned short* gbuf = qkv;    // alias: 44MB act spans qkv (49MB), dead during MLP

  rope_tables<<<S_, DH_, 0, stream>>>(cosT, sinT);
  embed_gather<<<M_, 256, 0, stream>>>(tok, embedw, hbuf);

  const int my = (M_ + 127) / 128;            // 32
  const dim3 gQKV((3 * D_ / 128) * my);       // 1536 blocks
  const dim3 gAtt((D_ / 128) * my, 1, 2);     // 512 x 2 (k-split) = 1024
  const dim3 gMlp((DFF_ / 128) * my, 1, 2);   // 1376 x 2 (G,U pair) = 2752
  const size_t DD = (size_t)D_ * D_;
  const size_t FD = (size_t)DFF_ * D_;

  for (int l = 0; l < L_N; ++l) {
    const int*   wqi = wq_idx + (size_t)l * DD;
    const float* wqs = wq_sc + (size_t)l * D_ * (D_ / 64);
    const int*   wki = wk_idx + (size_t)l * DD;
    const float* wks = wk_sc + (size_t)l * D_ * (D_ / 64);
    const int*   wvi = wv_idx + (size_t)l * DD;
    const float* wvs = wv_sc + (size_t)l * D_ * (D_ / 64);
    const int*   woi = wo_idx + (size_t)l * DD;
    const float* wos = wo_sc + (size_t)l * D_ * (D_ / 64);
    const int*   wgi = wg_idx + (size_t)l * FD;
    const float* wgs = wg_sc + (size_t)l * DFF_ * (D_ / 64);
    const int*   wui = wu_idx + (size_t)l * FD;
    const float* wus = wu_sc + (size_t)l * DFF_ * (D_ / 64);
    const int*   wdi = wd_idx + (size_t)l * FD;
    const float* wds = wd_sc + (size_t)l * D_ * (DFF_ / 64);

    // ln1: plain for layer 0; merged with previous D-split partial otherwise
    rmsnorm_k<<<M_, 256, 0, stream>>>(hbuf, l == 0 ? nullptr : dscr, ln1 + l * D_, xn);

    // batch 1: Q,K,V,O -> wdeq[0..4*DD)
    {
      DqBatch bt;
      bt.j[0] = { wqi, wqs, wdeq };
      bt.j[1] = { wki, wks, wdeq + DD };
      bt.j[2] = { wvi, wvs, wdeq + 2 * DD };
      bt.j[3] = { woi, wos, wdeq + 3 * DD };
      dequant_batch<<<dim3(1, D_, 4), 256, 0, stream>>>(bt, D_);
    }
    gemm_pipe<1><<<gQKV, 256, 0, stream>>>(xn, wdeq, nullptr, M_, 3 * D_, D_,
                                           qkv, nullptr);
    rope_apply<<<(B_ * H_ * S_ * 64) / 256, 256, 0, stream>>>(qb, kb, cosT, sinT);
    vtrans_k<<<dim3(16, 2, B_ * H_), 256, 0, stream>>>(vb, vt);
    attn2_k<<<dim3(B_ * H_, 8), 512, 0, stream>>>(qb, kb, vt, ctx);
    // O-GEMM k-split (control path): z0 -> hbuf += (kt 0..15), z1 -> dscr = (kt 16..31)
    gemm_bf16<3><<<gAtt, 256, 0, stream>>>(ctx, wdeq + 3 * DD, nullptr, M_, D_, D_,
                                           D_ / 128, 16, hbuf, nullptr, dscr);
    rmsnorm_k<<<M_, 256, 0, stream>>>(hbuf, dscr, ln2 + l * D_, xn);

    // batch 2: G,U -> wdeq[0..2*FD)
    {
      DqBatch bt;
      bt.j[0] = { wgi, wgs, wdeq };
      bt.j[1] = { wui, wus, wdeq + FD };
      bt.j[2] = bt.j[0]; bt.j[3] = bt.j[0];
      dequant_batch<<<dim3(1, DFF_, 2), 256, 0, stream>>>(bt, D_);
    }
    // G and U co-scheduled, PIPELINED (counted vmcnt)
    gemm_pipe<0><<<gMlp, 256, 0, stream>>>(xn, wdeq, wdeq + FD, M_, DFF_, D_,
                                           gbuf, ubuf);
    silu_mul<<<(M_ * DFF_ / 8) / 256, 256, 0, stream>>>(gbuf, ubuf);

    // batch 3: D (K = DFF)
    {
      DqBatch bt;
      bt.j[0] = { wdi, wds, wdeq };
      bt.j[1] = bt.j[0]; bt.j[2] = bt.j[0]; bt.j[3] = bt.j[0];
      dequant_batch<<<dim3(3, D_, 1), 256, 0, stream>>>(bt, DFF_);
    }
    // D-GEMM k-split (control path): z0 -> hbuf += (kt 0..42), z1 -> dscr = (kt 43..85)
    gemm_bf16<3><<<gAtt, 256, 0, stream>>>(gbuf, wdeq, nullptr, M_, D_, DFF_,
                                           D_ / 128, 43, hbuf, nullptr, dscr);
  }

  rmsnorm_k<<<M_, 256, 0, stream>>>(hbuf, dscr, lnf, xn);
  meanpool<<<dim3(D_ / 256, B_), 256, 0, stream>>>(xn, out);
  series_k<<<B_, 256, 0, stream>>>(x, projw, projb, out);
}

// Round 11
// 1388.121 us; speedup vs baseline: 1.0268x; 1.0268x over previous
//
#include <hip/hip_runtime.h>
#include <hip/hip_bf16.h>

#define L_N 2
#define D_ 2048
#define H_ 16
#define DH_ 128
#define DFF_ 5504
#define B_ 4
#define S_ 1000
#define C_ 7
#define T_ 45
#define M_ 4000   // B_*S_

typedef short bf16x8 __attribute__((ext_vector_type(8)));
typedef float f32x4 __attribute__((ext_vector_type(4)));

__constant__ float NF4_TAB[16] = {
  -1.0f, -0.6961928009986877f, -0.5250730514526367f, -0.39491748809814453f,
  -0.28444138169288635f, -0.18477343022823334f, -0.09105003625154495f, 0.0f,
  0.07958029955625534f, 0.16093020141124725f, 0.24611230194568634f,
  0.3379152417182922f, 0.44070982933044434f, 0.5626170039176941f,
  0.7229568362236023f, 1.0f };

__device__ __forceinline__ unsigned short f2bf(float f) {
  unsigned int u = __float_as_uint(f);
  u += 0x7fffu + ((u >> 16) & 1u);          // RNE
  return (unsigned short)(u >> 16);
}
__device__ __forceinline__ float bf2f(unsigned short u) {
  return __uint_as_float(((unsigned int)u) << 16);
}
__device__ __forceinline__ f32x4 zero4() { f32x4 z; z[0]=0.f; z[1]=0.f; z[2]=0.f; z[3]=0.f; return z; }
__device__ __forceinline__ f32x4 mfma16(bf16x8 a, bf16x8 b, f32x4 c) {
  return __builtin_amdgcn_mfma_f32_16x16x32_bf16(a, b, c, 0, 0, 0);
}

typedef __attribute__((address_space(3))) unsigned int lds_u32;
typedef const __attribute__((address_space(1))) unsigned int glb_u32;
__device__ __forceinline__ void gload16(const void* g, void* l) {
  __builtin_amdgcn_global_load_lds((glb_u32*)g, (lds_u32*)l, 16, 0, 0);
}

// ---------------- rope tables ----------------
__global__ void rope_tables(float* __restrict__ cosT, float* __restrict__ sinT) {
  int s = blockIdx.x, d = threadIdx.x;   // 128 threads
  int j = d & 63;
  float inv = expf(-(float)j * (9.210340371976184f / 64.f)); // 10000^(-j/64)
  float ang = (float)s * inv;
  cosT[s * DH_ + d] = cosf(ang);
  sinT[s * DH_ + d] = sinf(ang);
}

// ---------------- embedding gather ----------------
__global__ __launch_bounds__(256) void embed_gather(const int* __restrict__ tok,
    const float* __restrict__ emb, float* __restrict__ h) {
  int row = blockIdx.x;                 // 0..3999  (b*S+s)
  int tk = tok[row];
  const float4* src = reinterpret_cast<const float4*>(emb + (size_t)tk * D_);
  float4* dst = reinterpret_cast<float4*>(h + (size_t)row * D_);
  dst[threadIdx.x] = src[threadIdx.x];
  dst[threadIdx.x + 256] = src[threadIdx.x + 256];
}

// ---------------- rmsnorm (+optional k-split merge): fp32 in -> bf16 out ----------------
__global__ __launch_bounds__(256) void rmsnorm_k(float* __restrict__ h,
    const float* __restrict__ add, const float* __restrict__ w,
    unsigned short* __restrict__ out) {
  const int row = blockIdx.x, t = threadIdx.x;
  float* hp = h + (size_t)row * D_;
  float4 a = *reinterpret_cast<const float4*>(&hp[t * 8]);
  float4 b = *reinterpret_cast<const float4*>(&hp[t * 8 + 4]);
  if (add) {
    const float* ap = add + (size_t)row * D_;
    float4 da = *reinterpret_cast<const float4*>(&ap[t * 8]);
    float4 db = *reinterpret_cast<const float4*>(&ap[t * 8 + 4]);
    a.x += da.x; a.y += da.y; a.z += da.z; a.w += da.w;
    b.x += db.x; b.y += db.y; b.z += db.z; b.w += db.w;
    *reinterpret_cast<float4*>(&hp[t * 8]) = a;
    *reinterpret_cast<float4*>(&hp[t * 8 + 4]) = b;
  }
  float ss = a.x*a.x + a.y*a.y + a.z*a.z + a.w*a.w
           + b.x*b.x + b.y*b.y + b.z*b.z + b.w*b.w;
#pragma unroll
  for (int m = 1; m < 64; m <<= 1) ss += __shfl_xor(ss, m);
  __shared__ float red[4];
  if ((t & 63) == 0) red[t >> 6] = ss;
  __syncthreads();
  float tot = red[0] + red[1] + red[2] + red[3];
  float rs = rsqrtf(tot * (1.0f / D_) + 1e-5f);
  float4 wa = *reinterpret_cast<const float4*>(&w[t * 8]);
  float4 wb = *reinterpret_cast<const float4*>(&w[t * 8 + 4]);
  unsigned r0 = (unsigned)f2bf(a.x*rs*wa.x) | ((unsigned)f2bf(a.y*rs*wa.y) << 16);
  unsigned r1 = (unsigned)f2bf(a.z*rs*wa.z) | ((unsigned)f2bf(a.w*rs*wa.w) << 16);
  unsigned r2 = (unsigned)f2bf(b.x*rs*wb.x) | ((unsigned)f2bf(b.y*rs*wb.y) << 16);
  unsigned r3 = (unsigned)f2bf(b.z*rs*wb.z) | ((unsigned)f2bf(b.w*rs*wb.w) << 16);
  int4 ov; ov.x = (int)r0; ov.y = (int)r1; ov.z = (int)r2; ov.w = (int)r3;
  *reinterpret_cast<int4*>(&out[(size_t)row * D_ + t * 8]) = ov;
}

// ---------------- batched NF4 dequant: up to 4 matrices, uniform K ----------------
struct DqJob { const int* idx; const float* sc; unsigned short* out; };
struct DqBatch { DqJob j[4]; };

__global__ __launch_bounds__(256) void dequant_batch(DqBatch bt, int K) {
  __shared__ float nf4[16];
  const int t = threadIdx.x;
  if (t < 16) nf4[t] = NF4_TAB[t];
  __syncthreads();
  const DqJob jb = bt.j[blockIdx.z];
  const int row = blockIdx.y;
  const int k0 = blockIdx.x * 2048 + t * 8;
  if (k0 >= K) return;
  const size_t base = (size_t)row * K + k0;
  int4 a = *reinterpret_cast<const int4*>(&jb.idx[base]);
  int4 b = *reinterpret_cast<const int4*>(&jb.idx[base + 4]);
  float s = jb.sc[(size_t)row * (K >> 6) + (k0 >> 6)];
  unsigned r0 = (unsigned)f2bf(nf4[a.x & 15] * s) | ((unsigned)f2bf(nf4[a.y & 15] * s) << 16);
  unsigned r1 = (unsigned)f2bf(nf4[a.z & 15] * s) | ((unsigned)f2bf(nf4[a.w & 15] * s) << 16);
  unsigned r2 = (unsigned)f2bf(nf4[b.x & 15] * s) | ((unsigned)f2bf(nf4[b.y & 15] * s) << 16);
  unsigned r3 = (unsigned)f2bf(nf4[b.z & 15] * s) | ((unsigned)f2bf(nf4[b.w & 15] * s) << 16);
  int4 ov; ov.x = (int)r0; ov.y = (int)r1; ov.z = (int)r2; ov.w = (int)r3;
  *reinterpret_cast<int4*>(&jb.out[base]) = ov;
}

// ---------------- bf16 GEMM (single-buffer 2-phase, swizzled LDS) --------
// MODE 1: out bf16 qkv layout [which][B][H][S][DH] (which = gn>>11)
// MODE 3: fp32 k-split: z==0 (kt in [0,ksplit)) -> outp += acc;
//                       z==1 (kt in [ksplit,kT)) -> dscr = acc
template<int MODE>
__global__ __launch_bounds__(256, 4) void gemm_bf16(
    const unsigned short* __restrict__ A,
    const unsigned short* __restrict__ Bw,
    int Mdim, int N, int K, int ksplit,
    void* outp, float* dscr) {
  __shared__ unsigned short A_lds[128 * 64];   // XOR-swizzled rows, 16 KiB
  __shared__ unsigned short B_lds[128 * 64];
  const int t = threadIdx.x;
  const int lane = t & 63, wid = t >> 6;
  const int z = blockIdx.z;

  // XCD-banded m-grouped mapping (my == 32 == 8 xcd * 4 for all launches)
  const int bid = blockIdx.x;
  const int xcd = bid & 7, l = bid >> 3;
  const int m_blk = xcd * 4 + (l & 3);
  const int n_blk = l >> 2;
  const int n0 = n_blk * 128;
  const int m0 = m_blk * 128;

  const int wm = (wid >> 1) * 64, wn = (wid & 1) * 64;
  const int lr = lane & 15, lg = lane >> 4;
  const int lrow = lane >> 3;
  const int lslot = (((lane & 7) ^ lrow) << 4);
  const int rswz = (lr & 7) << 4;

  f32x4 acc[4][4];
#pragma unroll
  for (int i = 0; i < 4; ++i)
#pragma unroll
    for (int j = 0; j < 4; ++j) acc[i][j] = zero4();

  const int kT = K >> 6;
  const int ktlo = (MODE == 3) ? (z ? ksplit : 0) : 0;
  const int kthi = (MODE == 3) ? (z ? kT : ksplit) : kT;
  const size_t rowb = (size_t)(K * 2);

  for (int kt = ktlo; kt < kthi; ++kt) {
#pragma unroll
    for (int c0 = 0; c0 < 4; ++c0) {
      const int c = wid + 4 * c0;
      int gr = m0 + c * 8 + lrow;
      gr = gr < Mdim ? gr : Mdim - 1;
      gload16((const char*)A + (size_t)gr * rowb + kt * 128 + lslot,
              (char*)&A_lds[0] + c * 1024);
      const int nr = n0 + c * 8 + lrow;
      gload16((const char*)Bw + (size_t)nr * rowb + kt * 128 + lslot,
              (char*)&B_lds[0] + c * 1024);
    }
    __syncthreads();
#pragma unroll
    for (int ks = 0; ks < 2; ++ks) {
      bf16x8 af[4], bfr[4];
      const int cb = (ks * 64 + lg * 16) ^ rswz;
#pragma unroll
      for (int i = 0; i < 4; ++i) {
        af[i]  = *reinterpret_cast<const bf16x8*>(
                   (const char*)&A_lds[0] + (wm + i * 16 + lr) * 128 + cb);
        bfr[i] = *reinterpret_cast<const bf16x8*>(
                   (const char*)&B_lds[0] + (wn + i * 16 + lr) * 128 + cb);
      }
      __builtin_amdgcn_s_setprio(1);
#pragma unroll
      for (int mi = 0; mi < 4; ++mi)
#pragma unroll
        for (int ni = 0; ni < 4; ++ni)
          acc[mi][ni] = mfma16(af[mi], bfr[ni], acc[mi][ni]);
      __builtin_amdgcn_s_setprio(0);
    }
    __syncthreads();
  }

#pragma unroll
  for (int mi = 0; mi < 4; ++mi) {
#pragma unroll
    for (int r = 0; r < 4; ++r) {
      int gm = m0 + wm + mi * 16 + lg * 4 + r;
      if (gm >= Mdim) continue;
#pragma unroll
      for (int ni = 0; ni < 4; ++ni) {
        int gn = n0 + wn + ni * 16 + lr;
        float v = acc[mi][ni][r];
        if (MODE == 1) {
          const int which = gn >> 11;
          const int hh = (gn >> 7) & 15, dd = gn & 127;
          const int b = gm / S_, s = gm - b * S_;
          ((unsigned short*)outp)[
            (((size_t)which * (B_ * H_) + b * H_ + hh) * S_ + s) * DH_ + dd] = f2bf(v);
        } else {
          if (z == 0) ((float*)outp)[(size_t)gm * N + gn] += v;
          else        dscr[(size_t)gm * N + gn] = v;
        }
      }
    }
  }
}

// ======== fused gate/up GEMM: out = silu(A@Wg^T) * (A@Wu^T), bf16 ========
// Two K-passes per block over the same 128x128 output tile; g held packed-bf16
// in 32 VGPRs between passes (same precision as the old bf16 round-trip).
__global__ __launch_bounds__(256, 4) void gemm_gu(
    const unsigned short* __restrict__ A,
    const unsigned short* __restrict__ Bg,
    const unsigned short* __restrict__ Bu,
    int Mdim, int N, int K,
    unsigned short* __restrict__ outp) {
  __shared__ unsigned short A_lds[128 * 64];
  __shared__ unsigned short B_lds[128 * 64];
  const int t = threadIdx.x;
  const int lane = t & 63, wid = t >> 6;

  const int bid = blockIdx.x;
  const int xcd = bid & 7, l = bid >> 3;
  const int m_blk = xcd * 4 + (l & 3);
  const int n_blk = l >> 2;
  const int n0 = n_blk * 128;
  const int m0 = m_blk * 128;

  const int wm = (wid >> 1) * 64, wn = (wid & 1) * 64;
  const int lr = lane & 15, lg = lane >> 4;
  const int lrow = lane >> 3;
  const int lslot = (((lane & 7) ^ lrow) << 4);
  const int rswz = (lr & 7) << 4;

  const int kT = K >> 6;
  const size_t rowb = (size_t)(K * 2);

  f32x4 acc[4][4];
  unsigned pg[4][4][2];   // packed bf16 gate tile (32 VGPRs)

  auto kloop = [&](const unsigned short* Bsrc) {
    for (int kt = 0; kt < kT; ++kt) {
#pragma unroll
      for (int c0 = 0; c0 < 4; ++c0) {
        const int c = wid + 4 * c0;
        int gr = m0 + c * 8 + lrow;
        gr = gr < Mdim ? gr : Mdim - 1;
        gload16((const char*)A + (size_t)gr * rowb + kt * 128 + lslot,
                (char*)&A_lds[0] + c * 1024);
        const int nr = n0 + c * 8 + lrow;
        gload16((const char*)Bsrc + (size_t)nr * rowb + kt * 128 + lslot,
                (char*)&B_lds[0] + c * 1024);
      }
      __syncthreads();
#pragma unroll
      for (int ks = 0; ks < 2; ++ks) {
        bf16x8 af[4], bfr[4];
        const int cb = (ks * 64 + lg * 16) ^ rswz;
#pragma unroll
        for (int i = 0; i < 4; ++i) {
          af[i]  = *reinterpret_cast<const bf16x8*>(
                     (const char*)&A_lds[0] + (wm + i * 16 + lr) * 128 + cb);
          bfr[i] = *reinterpret_cast<const bf16x8*>(
                     (const char*)&B_lds[0] + (wn + i * 16 + lr) * 128 + cb);
        }
        __builtin_amdgcn_s_setprio(1);
#pragma unroll
        for (int mi = 0; mi < 4; ++mi)
#pragma unroll
          for (int ni = 0; ni < 4; ++ni)
            acc[mi][ni] = mfma16(af[mi], bfr[ni], acc[mi][ni]);
        __builtin_amdgcn_s_setprio(0);
      }
      __syncthreads();
    }
  };

  // pass 1: gate
#pragma unroll
  for (int i = 0; i < 4; ++i)
#pragma unroll
    for (int j = 0; j < 4; ++j) acc[i][j] = zero4();
  kloop(Bg);
#pragma unroll
  for (int mi = 0; mi < 4; ++mi)
#pragma unroll
    for (int ni = 0; ni < 4; ++ni) {
      pg[mi][ni][0] = (unsigned)f2bf(acc[mi][ni][0]) | ((unsigned)f2bf(acc[mi][ni][1]) << 16);
      pg[mi][ni][1] = (unsigned)f2bf(acc[mi][ni][2]) | ((unsigned)f2bf(acc[mi][ni][3]) << 16);
      acc[mi][ni] = zero4();
    }

  // pass 2: up
  kloop(Bu);

  // epilogue: silu(g) * u
#pragma unroll
  for (int mi = 0; mi < 4; ++mi) {
#pragma unroll
    for (int r = 0; r < 4; ++r) {
      int gm = m0 + wm + mi * 16 + lg * 4 + r;
      if (gm >= Mdim) continue;
#pragma unroll
      for (int ni = 0; ni < 4; ++ni) {
        int gn = n0 + wn + ni * 16 + lr;
        float g = bf2f((unsigned short)((pg[mi][ni][r >> 1] >> ((r & 1) * 16)) & 0xffffu));
        float sg = g / (1.f + __expf(-g));
        outp[(size_t)gm * N + gn] = f2bf(sg * acc[mi][ni][r]);
      }
    }
  }
}

// ---------------- rope apply (in-place, q & k) ----------------
__global__ __launch_bounds__(256) void rope_apply(unsigned short* __restrict__ qb,
    unsigned short* __restrict__ kb, const float* __restrict__ cosT,
    const float* __restrict__ sinT) {
  size_t i = (size_t)blockIdx.x * 256 + threadIdx.x;  // B*H*S*64 slots
  int d = (int)(i & 63);
  size_t row = i >> 6;              // (b*H+h)*S + s
  int s = (int)(row % S_);
  size_t base = row * DH_;
  float c = cosT[s * DH_ + d], sn = sinT[s * DH_ + d];
  float q0 = bf2f(qb[base + d]), q1 = bf2f(qb[base + d + 64]);
  qb[base + d]      = f2bf(q0 * c - q1 * sn);
  qb[base + d + 64] = f2bf(q1 * c + q0 * sn);
  float k0 = bf2f(kb[base + d]), k1 = bf2f(kb[base + d + 64]);
  kb[base + d]      = f2bf(k0 * c - k1 * sn);
  kb[base + d + 64] = f2bf(k1 * c + k0 * sn);
}

// ---------------- V transpose: vb [b][h][s][128] -> vt [bh][128][1024] ----------------
__global__ __launch_bounds__(256) void vtrans_k(const unsigned short* __restrict__ vb,
    unsigned short* __restrict__ vt) {
  __shared__ unsigned int tile[64][33];
  const int t = threadIdx.x;
  const int s0 = blockIdx.x * 64, d0 = blockIdx.y * 64, bh = blockIdx.z;
#pragma unroll
  for (int j = 0; j < 2; ++j) {
    int idx = t + 256 * j;
    int s_r = idx >> 3, c8 = (idx & 7) << 3;
    int srow = s0 + s_r; srow = srow < S_ ? srow : S_ - 1;
    int4 v = *reinterpret_cast<const int4*>(&vb[((size_t)bh * S_ + srow) * DH_ + d0 + c8]);
    tile[s_r][(c8 >> 1) + 0] = (unsigned)v.x;
    tile[s_r][(c8 >> 1) + 1] = (unsigned)v.y;
    tile[s_r][(c8 >> 1) + 2] = (unsigned)v.z;
    tile[s_r][(c8 >> 1) + 3] = (unsigned)v.w;
  }
  __syncthreads();
#pragma unroll
  for (int j = 0; j < 2; ++j) {
    int idx = t + 256 * j;
    int d_r = idx >> 3, s8 = (idx & 7) << 3;
    unsigned r[8];
#pragma unroll
    for (int e = 0; e < 8; ++e) {
      unsigned wv = tile[s8 + e][d_r >> 1];
      r[e] = (d_r & 1) ? (wv >> 16) : (wv & 0xffffu);
    }
    int4 ov;
    ov.x = (int)(r[0] | (r[1] << 16));
    ov.y = (int)(r[2] | (r[3] << 16));
    ov.z = (int)(r[4] | (r[5] << 16));
    ov.w = (int)(r[6] | (r[7] << 16));
    *reinterpret_cast<int4*>(&vt[((size_t)(bh * 128 + d0 + d_r)) * 1024 + s0 + s8]) = ov;
  }
}

// ---------------- causal flash attention v2 (swapped-QK, 8 waves, 128 q rows) --------
__global__ __launch_bounds__(512, 4) void attn2_k(const unsigned short* __restrict__ qg,
    const unsigned short* __restrict__ kg, const unsigned short* __restrict__ vtg,
    unsigned short* __restrict__ ctx) {
  __shared__ unsigned short K_lds[64 * 128];
  __shared__ unsigned short VT_lds[128 * 64];
  const int t = threadIdx.x, lane = t & 63, w = t >> 6;
  const int lr = lane & 15, lg = lane >> 4;
  const int bh = blockIdx.x, qt = blockIdx.y;
  const int q0 = qt * 128;
  const int b = bh >> 4, hh = bh & 15;
  const size_t kbase2 = (size_t)bh * S_ * DH_ * 2;   // byte base of this head
  const int q_idx = q0 + w * 16 + lr;
  const int swz = (lr & 7) << 4;

  bf16x8 qf[4];
#pragma unroll
  for (int ks = 0; ks < 4; ++ks) {
    bf16x8 z;
#pragma unroll
    for (int e = 0; e < 8; ++e) z[e] = 0;
    if (q_idx < S_)
      z = *reinterpret_cast<const bf16x8*>(
            (const char*)qg + kbase2 + (size_t)q_idx * 256 + ks * 64 + lg * 16);
    qf[ks] = z;
  }
  float mst = -1e30f, lst = 0.f;
  f32x4 cacc[8];
#pragma unroll
  for (int f = 0; f < 8; ++f) cacc[f] = zero4();

  const int q_hi = (q0 + 127 < S_) ? q0 + 127 : S_ - 1;
  const int nt = q_hi / 64 + 1;
  const int wq_max = q0 + w * 16 + 15;

  for (int kt = 0; kt < nt; ++kt) {
    const int kv0 = kt * 64;
    __syncthreads();
    // stage K [64][128] and VT [128][64], XOR-swizzled source -> linear LDS
#pragma unroll
    for (int j = 0; j < 2; ++j) {
      const int chunk = w + 8 * j;            // 0..15, 1024B each
      int krow = chunk * 4 + (lane >> 4);     // 4 rows x 256B
      int kcolb = (lane & 15) << 4;
      int gr = kv0 + krow; gr = gr < S_ ? gr : S_ - 1;
      gload16((const char*)kg + kbase2 + (size_t)gr * 256 + (kcolb ^ ((krow & 7) << 4)),
              (char*)K_lds + chunk * 1024);
      int vrow = chunk * 8 + (lane >> 3);     // 8 rows x 128B
      int vcolb = (lane & 7) << 4;
      gload16((const char*)vtg + ((size_t)(bh * 128 + vrow) * 1024 + kv0) * 2 + (vcolb ^ ((vrow & 7) << 4)),
              (char*)VT_lds + chunk * 1024);
    }
    __syncthreads();
    if (kv0 > wq_max) continue;               // whole wave masked this tile

    // S^T = K . Q^T  (row = kv, col = q = lr)
    f32x4 sacc[4];
#pragma unroll
    for (int c = 0; c < 4; ++c) sacc[c] = zero4();
#pragma unroll
    for (int ks = 0; ks < 4; ++ks) {
#pragma unroll
      for (int c = 0; c < 4; ++c) {
        bf16x8 kf = *reinterpret_cast<const bf16x8*>(
            &K_lds[(c * 16 + lr) * 128 + (((ks * 64 + lg * 16) ^ swz) >> 1)]);
        sacc[c] = mfma16(kf, qf[ks], sacc[c]);
      }
    }
    // mask + online softmax (per-lane scalar m/l; reduce across lg groups)
    float p[4][4];
    float mx = -1e30f;
#pragma unroll
    for (int c = 0; c < 4; ++c)
#pragma unroll
      for (int r = 0; r < 4; ++r) {
        int kv = kv0 + c * 16 + lg * 4 + r;
        float v = sacc[c][r] * 0.08838834764831845f;   // 1/sqrt(128)
        if (kv > q_idx || kv >= S_) v = -1e30f;
        p[c][r] = v;
        mx = fmaxf(mx, v);
      }
    mx = fmaxf(mx, __shfl_xor(mx, 16));
    mx = fmaxf(mx, __shfl_xor(mx, 32));
    float mn = fmaxf(mst, mx);
    float corr = __expf(mst - mn);
    mst = mn;
    float rs = 0.f;
#pragma unroll
    for (int c = 0; c < 4; ++c)
#pragma unroll
      for (int r = 0; r < 4; ++r) {
        float e = __expf(p[c][r] - mn);
        p[c][r] = e;
        rs += e;
      }
    rs += __shfl_xor(rs, 16);
    rs += __shfl_xor(rs, 32);
    lst = lst * corr + rs;
#pragma unroll
    for (int f = 0; f < 8; ++f)
#pragma unroll
      for (int r = 0; r < 4; ++r) cacc[f][r] *= corr;

    // pack P (bf16 pairs) and redistribute to PV B-operand via shfl
    unsigned pk01[4], pk23[4];
#pragma unroll
    for (int c = 0; c < 4; ++c) {
      pk01[c] = (unsigned)f2bf(p[c][0]) | ((unsigned)f2bf(p[c][1]) << 16);
      pk23[c] = (unsigned)f2bf(p[c][2]) | ((unsigned)f2bf(p[c][3]) << 16);
    }
#pragma unroll
    for (int ks = 0; ks < 2; ++ks) {
      unsigned bu[4];
#pragma unroll
      for (int jj = 0; jj < 4; ++jj) {
        const int srcl = ((lg & 1) * 2 + (jj >> 1)) * 16 + lr;
        unsigned lo = (unsigned)__shfl((int)((jj & 1) ? pk23[2 * ks]     : pk01[2 * ks]),     srcl);
        unsigned hi = (unsigned)__shfl((int)((jj & 1) ? pk23[2 * ks + 1] : pk01[2 * ks + 1]), srcl);
        bu[jj] = (lg >= 2) ? hi : lo;
      }
      union { unsigned u[4]; bf16x8 v; } pb;
      pb.u[0] = bu[0]; pb.u[1] = bu[1]; pb.u[2] = bu[2]; pb.u[3] = bu[3];
#pragma unroll
      for (int f = 0; f < 8; ++f) {
        bf16x8 vtf = *reinterpret_cast<const bf16x8*>(
            &VT_lds[(f * 16 + lr) * 64 + (((ks * 64 + lg * 16) ^ swz) >> 1)]);
        cacc[f] = mfma16(vtf, pb.v, cacc[f]);
      }
    }
  }

  // O^T frag: col = q = lr, row = d = f*16 + lg*4 + r  -> packed 8B stores
  if (q_idx < S_) {
    float inv = 1.f / lst;
    unsigned short* cp = ctx + ((size_t)(b * S_ + q_idx)) * D_ + hh * 128;
#pragma unroll
    for (int f = 0; f < 8; ++f) {
      unsigned lo = (unsigned)f2bf(cacc[f][0] * inv) | ((unsigned)f2bf(cacc[f][1] * inv) << 16);
      unsigned hi = (unsigned)f2bf(cacc[f][2] * inv) | ((unsigned)f2bf(cacc[f][3] * inv) << 16);
      uint2 ov; ov.x = lo; ov.y = hi;
      *reinterpret_cast<uint2*>(cp + f * 16 + lg * 4) = ov;
    }
  }
}

// ---------------- mean pool over sequence ----------------
__global__ __launch_bounds__(256) void meanpool(const unsigned short* __restrict__ xn,
    float* __restrict__ out) {
  int d = blockIdx.x * 256 + threadIdx.x;
  int b = blockIdx.y;
  const unsigned short* p = xn + (size_t)b * S_ * D_ + d;
  float s = 0.f;
  for (int i = 0; i < S_; ++i) s += bf2f(p[(size_t)i * D_]);
  out[(size_t)b * D_ + d] = s * (1.f / S_);
}

// ---------------- series branch: adds into out ----------------
__global__ __launch_bounds__(256) void series_k(const float* __restrict__ x,
    const float* __restrict__ pw, const float* __restrict__ pb, float* out) {
  __shared__ float sm[T_];
  __shared__ float emb[D_];
  __shared__ float red[4];
  int b = blockIdx.x, t = threadIdx.x;
  if (t < T_) {
    float s = 0.f;
    for (int c = 0; c < C_; ++c) s += x[((size_t)b * C_ + c) * T_ + t];
    sm[t] = s * (1.f / C_);
  }
  __syncthreads();
  float ssq = 0.f;
#pragma unroll
  for (int j = 0; j < D_ / 256; ++j) {
    int d = j * 256 + t;
    float e = pb[d];
    for (int tt = 0; tt < T_; ++tt) e += sm[tt] * pw[(size_t)d * T_ + tt];
    emb[d] = e;
    ssq += e * e;
  }
#pragma unroll
  for (int m = 1; m < 64; m <<= 1) ssq += __shfl_xor(ssq, m);
  if ((t & 63) == 0) red[t >> 6] = ssq;
  __syncthreads();
  float tot = red[0] + red[1] + red[2] + red[3];
  float inv = 1.f / fmaxf(sqrtf(tot), 1e-12f);
#pragma unroll
  for (int j = 0; j < D_ / 256; ++j) {
    int d = j * 256 + t;
    out[(size_t)b * D_ + d] += emb[d] * inv;
  }
}

extern "C" void kernel_launch(void* const* d_in, const int* in_sizes, int n_in,
                              void* d_out, int out_size, void* d_ws, size_t ws_size,
                              hipStream_t stream) {
  const float* x      = (const float*)d_in[0];
  const int*   tok    = (const int*)d_in[1];
  const float* embedw = (const float*)d_in[2];
  const int*   wq_idx = (const int*)d_in[3];
  const float* wq_sc  = (const float*)d_in[4];
  const int*   wk_idx = (const int*)d_in[5];
  const float* wk_sc  = (const float*)d_in[6];
  const int*   wv_idx = (const int*)d_in[7];
  const float* wv_sc  = (const float*)d_in[8];
  const int*   wo_idx = (const int*)d_in[9];
  const float* wo_sc  = (const float*)d_in[10];
  const int*   wg_idx = (const int*)d_in[11];
  const float* wg_sc  = (const float*)d_in[12];
  const int*   wu_idx = (const int*)d_in[13];
  const float* wu_sc  = (const float*)d_in[14];
  const int*   wd_idx = (const int*)d_in[15];
  const float* wd_sc  = (const float*)d_in[16];
  const float* ln1    = (const float*)d_in[17];
  const float* ln2    = (const float*)d_in[18];
  const float* lnf    = (const float*)d_in[19];
  const float* projw  = (const float*)d_in[20];
  const float* projb  = (const float*)d_in[21];
  float* out = (float*)d_out;
  (void)in_sizes; (void)n_in; (void)out_size; (void)ws_size;

  char* wsp = (char*)d_ws;
  size_t off = 0;
  auto alloc = [&](size_t bytes) -> void* {
    void* p = wsp + off; off += (bytes + 255) & ~(size_t)255; return p; };
  float* cosT = (float*)alloc((size_t)S_ * DH_ * 4);
  float* sinT = (float*)alloc((size_t)S_ * DH_ * 4);
  float* hbuf = (float*)alloc((size_t)M_ * D_ * 4);
  unsigned short* xn   = (unsigned short*)alloc((size_t)M_ * D_ * 2);
  unsigned short* qkv  = (unsigned short*)alloc((size_t)3 * B_ * H_ * S_ * DH_ * 2); // 49.2MB
  unsigned short* wdeq = (unsigned short*)alloc((size_t)2 * DFF_ * D_ * 2);          // 45.1MB
  unsigned short* vt   = (unsigned short*)alloc((size_t)B_ * H_ * DH_ * 1024 * 2);   // 16.8MB
  float* dscr = (float*)alloc((size_t)M_ * D_ * 4);                                  // 32.8MB
  const size_t NH = (size_t)B_ * H_ * S_ * DH_;
  unsigned short* qb = qkv, *kb = qkv + NH, *vb = qkv + 2 * NH;
  unsigned short* ctx  = xn;     // alias: xn dead during attention
  unsigned short* gbuf = qkv;    // alias: 44MB act spans qkv (49MB), dead during MLP

  rope_tables<<<S_, DH_, 0, stream>>>(cosT, sinT);
  embed_gather<<<M_, 256, 0, stream>>>(tok, embedw, hbuf);

  const int my = (M_ + 127) / 128;            // 32
  const dim3 gQKV((3 * D_ / 128) * my);       // 1536 blocks
  const dim3 gAtt((D_ / 128) * my, 1, 2);     // 512 x 2 (k-split) = 1024
  const dim3 gGU((DFF_ / 128) * my);          // 1376 blocks (fused G+U, 2 passes)
  const size_t DD = (size_t)D_ * D_;
  const size_t FD = (size_t)DFF_ * D_;

  for (int l = 0; l < L_N; ++l) {
    const int*   wqi = wq_idx + (size_t)l * DD;
    const float* wqs = wq_sc + (size_t)l * D_ * (D_ / 64);
    const int*   wki = wk_idx + (size_t)l * DD;
    const float* wks = wk_sc + (size_t)l * D_ * (D_ / 64);
    const int*   wvi = wv_idx + (size_t)l * DD;
    const float* wvs = wv_sc + (size_t)l * D_ * (D_ / 64);
    const int*   woi = wo_idx + (size_t)l * DD;
    const float* wos = wo_sc + (size_t)l * D_ * (D_ / 64);
    const int*   wgi = wg_idx + (size_t)l * FD;
    const float* wgs = wg_sc + (size_t)l * DFF_ * (D_ / 64);
    const int*   wui = wu_idx + (size_t)l * FD;
    const float* wus = wu_sc + (size_t)l * DFF_ * (D_ / 64);
    const int*   wdi = wd_idx + (size_t)l * FD;
    const float* wds = wd_sc + (size_t)l * D_ * (DFF_ / 64);

    // ln1: plain for layer 0; merged with previous D-split partial otherwise
    rmsnorm_k<<<M_, 256, 0, stream>>>(hbuf, l == 0 ? nullptr : dscr, ln1 + l * D_, xn);

    // batch 1: Q,K,V,O -> wdeq[0..4*DD)
    {
      DqBatch bt;
      bt.j[0] = { wqi, wqs, wdeq };
      bt.j[1] = { wki, wks, wdeq + DD };
      bt.j[2] = { wvi, wvs, wdeq + 2 * DD };
      bt.j[3] = { woi, wos, wdeq + 3 * DD };
      dequant_batch<<<dim3(1, D_, 4), 256, 0, stream>>>(bt, D_);
    }
    gemm_bf16<1><<<gQKV, 256, 0, stream>>>(xn, wdeq, M_, 3 * D_, D_, 0, qkv, nullptr);
    rope_apply<<<(B_ * H_ * S_ * 64) / 256, 256, 0, stream>>>(qb, kb, cosT, sinT);
    vtrans_k<<<dim3(16, 2, B_ * H_), 256, 0, stream>>>(vb, vt);
    attn2_k<<<dim3(B_ * H_, 8), 512, 0, stream>>>(qb, kb, vt, ctx);
    // O-GEMM k-split: z0 -> hbuf += (kt 0..15), z1 -> dscr = (kt 16..31)
    gemm_bf16<3><<<gAtt, 256, 0, stream>>>(ctx, wdeq + 3 * DD, M_, D_, D_, 16,
                                           hbuf, dscr);
    rmsnorm_k<<<M_, 256, 0, stream>>>(hbuf, dscr, ln2 + l * D_, xn);

    // batch 2: G,U -> wdeq[0..2*FD)
    {
      DqBatch bt;
      bt.j[0] = { wgi, wgs, wdeq };
      bt.j[1] = { wui, wus, wdeq + FD };
      bt.j[2] = bt.j[0]; bt.j[3] = bt.j[0];
      dequant_batch<<<dim3(1, DFF_, 2), 256, 0, stream>>>(bt, D_);
    }
    // fused: gbuf = silu(xn@Wg^T) * (xn@Wu^T)
    gemm_gu<<<gGU, 256, 0, stream>>>(xn, wdeq, wdeq + FD, M_, DFF_, D_, gbuf);

    // batch 3: D (K = DFF)
    {
      DqBatch bt;
      bt.j[0] = { wdi, wds, wdeq };
      bt.j[1] = bt.j[0]; bt.j[2] = bt.j[0]; bt.j[3] = bt.j[0];
      dequant_batch<<<dim3(3, D_, 1), 256, 0, stream>>>(bt, DFF_);
    }
    // D-GEMM k-split: z0 -> hbuf += (kt 0..42), z1 -> dscr = (kt 43..85)
    gemm_bf16<3><<<gAtt, 256, 0, stream>>>(gbuf, wdeq, M_, D_, DFF_, 43,
                                           hbuf, dscr);
  }

  rmsnorm_k<<<M_, 256, 0, stream>>>(hbuf, dscr, lnf, xn);
  meanpool<<<dim3(D_ / 256, B_), 256, 0, stream>>>(xn, out);
  series_k<<<B_, 256, 0, stream>>>(x, projw, projb, out);
}

// Round 12
// 1282.258 us; speedup vs baseline: 1.1116x; 1.0826x over previous
//
#include <hip/hip_runtime.h>
#include <hip/hip_bf16.h>

#define L_N 2
#define D_ 2048
#define H_ 16
#define DH_ 128
#define DFF_ 5504
#define B_ 4
#define S_ 1000
#define C_ 7
#define T_ 45
#define M_ 4000   // B_*S_

typedef short bf16x8 __attribute__((ext_vector_type(8)));
typedef float f32x4 __attribute__((ext_vector_type(4)));

__constant__ float NF4_TAB[16] = {
  -1.0f, -0.6961928009986877f, -0.5250730514526367f, -0.39491748809814453f,
  -0.28444138169288635f, -0.18477343022823334f, -0.09105003625154495f, 0.0f,
  0.07958029955625534f, 0.16093020141124725f, 0.24611230194568634f,
  0.3379152417182922f, 0.44070982933044434f, 0.5626170039176941f,
  0.7229568362236023f, 1.0f };

__device__ __forceinline__ unsigned short f2bf(float f) {
  unsigned int u = __float_as_uint(f);
  u += 0x7fffu + ((u >> 16) & 1u);          // RNE
  return (unsigned short)(u >> 16);
}
__device__ __forceinline__ float bf2f(unsigned short u) {
  return __uint_as_float(((unsigned int)u) << 16);
}
__device__ __forceinline__ f32x4 zero4() { f32x4 z; z[0]=0.f; z[1]=0.f; z[2]=0.f; z[3]=0.f; return z; }
__device__ __forceinline__ f32x4 mfma16(bf16x8 a, bf16x8 b, f32x4 c) {
  return __builtin_amdgcn_mfma_f32_16x16x32_bf16(a, b, c, 0, 0, 0);
}

typedef __attribute__((address_space(3))) unsigned int lds_u32;
typedef const __attribute__((address_space(1))) unsigned int glb_u32;
__device__ __forceinline__ void gload16(const void* g, void* l) {
  __builtin_amdgcn_global_load_lds((glb_u32*)g, (lds_u32*)l, 16, 0, 0);
}

// ---------------- rope tables ----------------
__global__ void rope_tables(float* __restrict__ cosT, float* __restrict__ sinT) {
  int s = blockIdx.x, d = threadIdx.x;   // 128 threads
  int j = d & 63;
  float inv = expf(-(float)j * (9.210340371976184f / 64.f)); // 10000^(-j/64)
  float ang = (float)s * inv;
  cosT[s * DH_ + d] = cosf(ang);
  sinT[s * DH_ + d] = sinf(ang);
}

// ---------------- embedding gather ----------------
__global__ __launch_bounds__(256) void embed_gather(const int* __restrict__ tok,
    const float* __restrict__ emb, float* __restrict__ h) {
  int row = blockIdx.x;                 // 0..3999  (b*S+s)
  int tk = tok[row];
  const float4* src = reinterpret_cast<const float4*>(emb + (size_t)tk * D_);
  float4* dst = reinterpret_cast<float4*>(h + (size_t)row * D_);
  dst[threadIdx.x] = src[threadIdx.x];
  dst[threadIdx.x + 256] = src[threadIdx.x + 256];
}

// ---------------- rmsnorm (+optional k-split merge): fp32 in -> bf16 out ----------------
__global__ __launch_bounds__(256) void rmsnorm_k(float* __restrict__ h,
    const float* __restrict__ add, const float* __restrict__ w,
    unsigned short* __restrict__ out) {
  const int row = blockIdx.x, t = threadIdx.x;
  float* hp = h + (size_t)row * D_;
  float4 a = *reinterpret_cast<const float4*>(&hp[t * 8]);
  float4 b = *reinterpret_cast<const float4*>(&hp[t * 8 + 4]);
  if (add) {
    const float* ap = add + (size_t)row * D_;
    float4 da = *reinterpret_cast<const float4*>(&ap[t * 8]);
    float4 db = *reinterpret_cast<const float4*>(&ap[t * 8 + 4]);
    a.x += da.x; a.y += da.y; a.z += da.z; a.w += da.w;
    b.x += db.x; b.y += db.y; b.z += db.z; b.w += db.w;
    *reinterpret_cast<float4*>(&hp[t * 8]) = a;
    *reinterpret_cast<float4*>(&hp[t * 8 + 4]) = b;
  }
  float ss = a.x*a.x + a.y*a.y + a.z*a.z + a.w*a.w
           + b.x*b.x + b.y*b.y + b.z*b.z + b.w*b.w;
#pragma unroll
  for (int m = 1; m < 64; m <<= 1) ss += __shfl_xor(ss, m);
  __shared__ float red[4];
  if ((t & 63) == 0) red[t >> 6] = ss;
  __syncthreads();
  float tot = red[0] + red[1] + red[2] + red[3];
  float rs = rsqrtf(tot * (1.0f / D_) + 1e-5f);
  float4 wa = *reinterpret_cast<const float4*>(&w[t * 8]);
  float4 wb = *reinterpret_cast<const float4*>(&w[t * 8 + 4]);
  unsigned r0 = (unsigned)f2bf(a.x*rs*wa.x) | ((unsigned)f2bf(a.y*rs*wa.y) << 16);
  unsigned r1 = (unsigned)f2bf(a.z*rs*wa.z) | ((unsigned)f2bf(a.w*rs*wa.w) << 16);
  unsigned r2 = (unsigned)f2bf(b.x*rs*wb.x) | ((unsigned)f2bf(b.y*rs*wb.y) << 16);
  unsigned r3 = (unsigned)f2bf(b.z*rs*wb.z) | ((unsigned)f2bf(b.w*rs*wb.w) << 16);
  int4 ov; ov.x = (int)r0; ov.y = (int)r1; ov.z = (int)r2; ov.w = (int)r3;
  *reinterpret_cast<int4*>(&out[(size_t)row * D_ + t * 8]) = ov;
}

// ---------------- batched NF4 dequant: up to 4 matrices, uniform K ----------------
struct DqJob { const int* idx; const float* sc; unsigned short* out; };
struct DqBatch { DqJob j[4]; };

__global__ __launch_bounds__(256) void dequant_batch(DqBatch bt, int K) {
  __shared__ float nf4[16];
  const int t = threadIdx.x;
  if (t < 16) nf4[t] = NF4_TAB[t];
  __syncthreads();
  const DqJob jb = bt.j[blockIdx.z];
  const int row = blockIdx.y;
  const int k0 = blockIdx.x * 2048 + t * 8;
  if (k0 >= K) return;
  const size_t base = (size_t)row * K + k0;
  int4 a = *reinterpret_cast<const int4*>(&jb.idx[base]);
  int4 b = *reinterpret_cast<const int4*>(&jb.idx[base + 4]);
  float s = jb.sc[(size_t)row * (K >> 6) + (k0 >> 6)];
  unsigned r0 = (unsigned)f2bf(nf4[a.x & 15] * s) | ((unsigned)f2bf(nf4[a.y & 15] * s) << 16);
  unsigned r1 = (unsigned)f2bf(nf4[a.z & 15] * s) | ((unsigned)f2bf(nf4[a.w & 15] * s) << 16);
  unsigned r2 = (unsigned)f2bf(nf4[b.x & 15] * s) | ((unsigned)f2bf(nf4[b.y & 15] * s) << 16);
  unsigned r3 = (unsigned)f2bf(nf4[b.z & 15] * s) | ((unsigned)f2bf(nf4[b.w & 15] * s) << 16);
  int4 ov; ov.x = (int)r0; ov.y = (int)r1; ov.z = (int)r2; ov.w = (int)r3;
  *reinterpret_cast<int4*>(&jb.out[base]) = ov;
}

// ---------------- bf16 GEMM (single-buffer 2-phase, swizzled LDS) --------
// C[M][N] = A[M][K] @ W[N][K]^T
// MODE 0: out bf16 [M][N].  blockIdx.z==1 -> use Bw2/outp2 (co-scheduled G/U pair)
// MODE 1: out bf16 qkv layout [which][B][H][S][DH] (which = gn>>11)
// MODE 3: fp32 k-split: z==0 (kt in [0,ksplit)) -> outp += acc;
//                       z==1 (kt in [ksplit,kT)) -> dscr = acc
template<int MODE>
__global__ __launch_bounds__(256, 4) void gemm_bf16(
    const unsigned short* __restrict__ A,
    const unsigned short* __restrict__ Bw,
    const unsigned short* __restrict__ Bw2,
    int Mdim, int N, int K, int ksplit,
    void* outp, void* outp2, float* dscr) {
  __shared__ unsigned short A_lds[128 * 64];   // XOR-swizzled rows, 16 KiB
  __shared__ unsigned short B_lds[128 * 64];
  const int t = threadIdx.x;
  const int lane = t & 63, wid = t >> 6;
  const int z = blockIdx.z;

  const unsigned short* Bsrc = (MODE == 0 && z) ? Bw2 : Bw;
  void* osel = (MODE == 0 && z) ? outp2 : outp;

  // XCD-banded m-grouped mapping (my == 32 == 8 xcd * 4 for all launches)
  const int bid = blockIdx.x;
  const int xcd = bid & 7, l = bid >> 3;
  const int m_blk = xcd * 4 + (l & 3);
  const int n_blk = l >> 2;
  const int n0 = n_blk * 128;
  const int m0 = m_blk * 128;

  const int wm = (wid >> 1) * 64, wn = (wid & 1) * 64;
  const int lr = lane & 15, lg = lane >> 4;
  const int lrow = lane >> 3;
  const int lslot = (((lane & 7) ^ lrow) << 4);
  const int rswz = (lr & 7) << 4;

  f32x4 acc[4][4];
#pragma unroll
  for (int i = 0; i < 4; ++i)
#pragma unroll
    for (int j = 0; j < 4; ++j) acc[i][j] = zero4();

  const int kT = K >> 6;
  const int ktlo = (MODE == 3) ? (z ? ksplit : 0) : 0;
  const int kthi = (MODE == 3) ? (z ? kT : ksplit) : kT;
  const size_t rowb = (size_t)(K * 2);

  for (int kt = ktlo; kt < kthi; ++kt) {
#pragma unroll
    for (int c0 = 0; c0 < 4; ++c0) {
      const int c = wid + 4 * c0;
      int gr = m0 + c * 8 + lrow;
      gr = gr < Mdim ? gr : Mdim - 1;
      gload16((const char*)A + (size_t)gr * rowb + kt * 128 + lslot,
              (char*)&A_lds[0] + c * 1024);
      const int nr = n0 + c * 8 + lrow;
      gload16((const char*)Bsrc + (size_t)nr * rowb + kt * 128 + lslot,
              (char*)&B_lds[0] + c * 1024);
    }
    __syncthreads();
#pragma unroll
    for (int ks = 0; ks < 2; ++ks) {
      bf16x8 af[4], bfr[4];
      const int cb = (ks * 64 + lg * 16) ^ rswz;
#pragma unroll
      for (int i = 0; i < 4; ++i) {
        af[i]  = *reinterpret_cast<const bf16x8*>(
                   (const char*)&A_lds[0] + (wm + i * 16 + lr) * 128 + cb);
        bfr[i] = *reinterpret_cast<const bf16x8*>(
                   (const char*)&B_lds[0] + (wn + i * 16 + lr) * 128 + cb);
      }
      __builtin_amdgcn_s_setprio(1);
#pragma unroll
      for (int mi = 0; mi < 4; ++mi)
#pragma unroll
        for (int ni = 0; ni < 4; ++ni)
          acc[mi][ni] = mfma16(af[mi], bfr[ni], acc[mi][ni]);
      __builtin_amdgcn_s_setprio(0);
    }
    __syncthreads();
  }

#pragma unroll
  for (int mi = 0; mi < 4; ++mi) {
#pragma unroll
    for (int r = 0; r < 4; ++r) {
      int gm = m0 + wm + mi * 16 + lg * 4 + r;
      if (gm >= Mdim) continue;
#pragma unroll
      for (int ni = 0; ni < 4; ++ni) {
        int gn = n0 + wn + ni * 16 + lr;
        float v = acc[mi][ni][r];
        if (MODE == 0) {
          ((unsigned short*)osel)[(size_t)gm * N + gn] = f2bf(v);
        } else if (MODE == 1) {
          const int which = gn >> 11;
          const int hh = (gn >> 7) & 15, dd = gn & 127;
          const int b = gm / S_, s = gm - b * S_;
          ((unsigned short*)outp)[
            (((size_t)which * (B_ * H_) + b * H_ + hh) * S_ + s) * DH_ + dd] = f2bf(v);
        } else {
          if (z == 0) ((float*)outp)[(size_t)gm * N + gn] += v;
          else        dscr[(size_t)gm * N + gn] = v;
        }
      }
    }
  }
}

// ---------------- silu-mul: g = silu(g) * u (elementwise, bf16) ----------------
__global__ __launch_bounds__(256) void silu_mul(unsigned short* __restrict__ g,
    const unsigned short* __restrict__ u) {
  const size_t i = ((size_t)blockIdx.x * 256 + threadIdx.x) * 8;
  int4 gv = *reinterpret_cast<const int4*>(&g[i]);
  int4 uv = *reinterpret_cast<const int4*>(&u[i]);
  const unsigned* gp = reinterpret_cast<const unsigned*>(&gv);
  const unsigned* up = reinterpret_cast<const unsigned*>(&uv);
  unsigned ov[4];
#pragma unroll
  for (int j = 0; j < 4; ++j) {
    float g0 = bf2f(gp[j] & 0xffffu), g1 = bf2f(gp[j] >> 16);
    float u0 = bf2f(up[j] & 0xffffu), u1 = bf2f(up[j] >> 16);
    float s0 = g0 / (1.f + __expf(-g0)) * u0;
    float s1 = g1 / (1.f + __expf(-g1)) * u1;
    ov[j] = (unsigned)f2bf(s0) | ((unsigned)f2bf(s1) << 16);
  }
  int4 o; o.x = (int)ov[0]; o.y = (int)ov[1]; o.z = (int)ov[2]; o.w = (int)ov[3];
  *reinterpret_cast<int4*>(&g[i]) = o;
}

// ---------------- rope apply (in-place, q & k) ----------------
__global__ __launch_bounds__(256) void rope_apply(unsigned short* __restrict__ qb,
    unsigned short* __restrict__ kb, const float* __restrict__ cosT,
    const float* __restrict__ sinT) {
  size_t i = (size_t)blockIdx.x * 256 + threadIdx.x;  // B*H*S*64 slots
  int d = (int)(i & 63);
  size_t row = i >> 6;              // (b*H+h)*S + s
  int s = (int)(row % S_);
  size_t base = row * DH_;
  float c = cosT[s * DH_ + d], sn = sinT[s * DH_ + d];
  float q0 = bf2f(qb[base + d]), q1 = bf2f(qb[base + d + 64]);
  qb[base + d]      = f2bf(q0 * c - q1 * sn);
  qb[base + d + 64] = f2bf(q1 * c + q0 * sn);
  float k0 = bf2f(kb[base + d]), k1 = bf2f(kb[base + d + 64]);
  kb[base + d]      = f2bf(k0 * c - k1 * sn);
  kb[base + d + 64] = f2bf(k1 * c + k0 * sn);
}

// ---------------- V transpose: vb [b][h][s][128] -> vt [bh][128][1024] ----------------
__global__ __launch_bounds__(256) void vtrans_k(const unsigned short* __restrict__ vb,
    unsigned short* __restrict__ vt) {
  __shared__ unsigned int tile[64][33];
  const int t = threadIdx.x;
  const int s0 = blockIdx.x * 64, d0 = blockIdx.y * 64, bh = blockIdx.z;
#pragma unroll
  for (int j = 0; j < 2; ++j) {
    int idx = t + 256 * j;
    int s_r = idx >> 3, c8 = (idx & 7) << 3;
    int srow = s0 + s_r; srow = srow < S_ ? srow : S_ - 1;
    int4 v = *reinterpret_cast<const int4*>(&vb[((size_t)bh * S_ + srow) * DH_ + d0 + c8]);
    tile[s_r][(c8 >> 1) + 0] = (unsigned)v.x;
    tile[s_r][(c8 >> 1) + 1] = (unsigned)v.y;
    tile[s_r][(c8 >> 1) + 2] = (unsigned)v.z;
    tile[s_r][(c8 >> 1) + 3] = (unsigned)v.w;
  }
  __syncthreads();
#pragma unroll
  for (int j = 0; j < 2; ++j) {
    int idx = t + 256 * j;
    int d_r = idx >> 3, s8 = (idx & 7) << 3;
    unsigned r[8];
#pragma unroll
    for (int e = 0; e < 8; ++e) {
      unsigned wv = tile[s8 + e][d_r >> 1];
      r[e] = (d_r & 1) ? (wv >> 16) : (wv & 0xffffu);
    }
    int4 ov;
    ov.x = (int)(r[0] | (r[1] << 16));
    ov.y = (int)(r[2] | (r[3] << 16));
    ov.z = (int)(r[4] | (r[5] << 16));
    ov.w = (int)(r[6] | (r[7] << 16));
    *reinterpret_cast<int4*>(&vt[((size_t)(bh * 128 + d0 + d_r)) * 1024 + s0 + s8]) = ov;
  }
}

// ---------------- causal flash attention v2 (swapped-QK, 8 waves, 128 q rows) --------
__global__ __launch_bounds__(512, 4) void attn2_k(const unsigned short* __restrict__ qg,
    const unsigned short* __restrict__ kg, const unsigned short* __restrict__ vtg,
    unsigned short* __restrict__ ctx) {
  __shared__ unsigned short K_lds[64 * 128];
  __shared__ unsigned short VT_lds[128 * 64];
  const int t = threadIdx.x, lane = t & 63, w = t >> 6;
  const int lr = lane & 15, lg = lane >> 4;
  const int bh = blockIdx.x, qt = blockIdx.y;
  const int q0 = qt * 128;
  const int b = bh >> 4, hh = bh & 15;
  const size_t kbase2 = (size_t)bh * S_ * DH_ * 2;   // byte base of this head
  const int q_idx = q0 + w * 16 + lr;
  const int swz = (lr & 7) << 4;

  bf16x8 qf[4];
#pragma unroll
  for (int ks = 0; ks < 4; ++ks) {
    bf16x8 z;
#pragma unroll
    for (int e = 0; e < 8; ++e) z[e] = 0;
    if (q_idx < S_)
      z = *reinterpret_cast<const bf16x8*>(
            (const char*)qg + kbase2 + (size_t)q_idx * 256 + ks * 64 + lg * 16);
    qf[ks] = z;
  }
  float mst = -1e30f, lst = 0.f;
  f32x4 cacc[8];
#pragma unroll
  for (int f = 0; f < 8; ++f) cacc[f] = zero4();

  const int q_hi = (q0 + 127 < S_) ? q0 + 127 : S_ - 1;
  const int nt = q_hi / 64 + 1;
  const int wq_max = q0 + w * 16 + 15;

  for (int kt = 0; kt < nt; ++kt) {
    const int kv0 = kt * 64;
    __syncthreads();
    // stage K [64][128] and VT [128][64], XOR-swizzled source -> linear LDS
#pragma unroll
    for (int j = 0; j < 2; ++j) {
      const int chunk = w + 8 * j;            // 0..15, 1024B each
      int krow = chunk * 4 + (lane >> 4);     // 4 rows x 256B
      int kcolb = (lane & 15) << 4;
      int gr = kv0 + krow; gr = gr < S_ ? gr : S_ - 1;
      gload16((const char*)kg + kbase2 + (size_t)gr * 256 + (kcolb ^ ((krow & 7) << 4)),
              (char*)K_lds + chunk * 1024);
      int vrow = chunk * 8 + (lane >> 3);     // 8 rows x 128B
      int vcolb = (lane & 7) << 4;
      gload16((const char*)vtg + ((size_t)(bh * 128 + vrow) * 1024 + kv0) * 2 + (vcolb ^ ((vrow & 7) << 4)),
              (char*)VT_lds + chunk * 1024);
    }
    __syncthreads();
    if (kv0 > wq_max) continue;               // whole wave masked this tile

    // S^T = K . Q^T  (row = kv, col = q = lr)
    f32x4 sacc[4];
#pragma unroll
    for (int c = 0; c < 4; ++c) sacc[c] = zero4();
#pragma unroll
    for (int ks = 0; ks < 4; ++ks) {
#pragma unroll
      for (int c = 0; c < 4; ++c) {
        bf16x8 kf = *reinterpret_cast<const bf16x8*>(
            &K_lds[(c * 16 + lr) * 128 + (((ks * 64 + lg * 16) ^ swz) >> 1)]);
        sacc[c] = mfma16(kf, qf[ks], sacc[c]);
      }
    }
    // mask + online softmax (per-lane scalar m/l; reduce across lg groups)
    float p[4][4];
    float mx = -1e30f;
#pragma unroll
    for (int c = 0; c < 4; ++c)
#pragma unroll
      for (int r = 0; r < 4; ++r) {
        int kv = kv0 + c * 16 + lg * 4 + r;
        float v = sacc[c][r] * 0.08838834764831845f;   // 1/sqrt(128)
        if (kv > q_idx || kv >= S_) v = -1e30f;
        p[c][r] = v;
        mx = fmaxf(mx, v);
      }
    mx = fmaxf(mx, __shfl_xor(mx, 16));
    mx = fmaxf(mx, __shfl_xor(mx, 32));
    float mn = fmaxf(mst, mx);
    float corr = __expf(mst - mn);
    mst = mn;
    float rs = 0.f;
#pragma unroll
    for (int c = 0; c < 4; ++c)
#pragma unroll
      for (int r = 0; r < 4; ++r) {
        float e = __expf(p[c][r] - mn);
        p[c][r] = e;
        rs += e;
      }
    rs += __shfl_xor(rs, 16);
    rs += __shfl_xor(rs, 32);
    lst = lst * corr + rs;
#pragma unroll
    for (int f = 0; f < 8; ++f)
#pragma unroll
      for (int r = 0; r < 4; ++r) cacc[f][r] *= corr;

    // pack P (bf16 pairs) and redistribute to PV B-operand via shfl
    unsigned pk01[4], pk23[4];
#pragma unroll
    for (int c = 0; c < 4; ++c) {
      pk01[c] = (unsigned)f2bf(p[c][0]) | ((unsigned)f2bf(p[c][1]) << 16);
      pk23[c] = (unsigned)f2bf(p[c][2]) | ((unsigned)f2bf(p[c][3]) << 16);
    }
#pragma unroll
    for (int ks = 0; ks < 2; ++ks) {
      unsigned bu[4];
#pragma unroll
      for (int jj = 0; jj < 4; ++jj) {
        const int srcl = ((lg & 1) * 2 + (jj >> 1)) * 16 + lr;
        unsigned lo = (unsigned)__shfl((int)((jj & 1) ? pk23[2 * ks]     : pk01[2 * ks]),     srcl);
        unsigned hi = (unsigned)__shfl((int)((jj & 1) ? pk23[2 * ks + 1] : pk01[2 * ks + 1]), srcl);
        bu[jj] = (lg >= 2) ? hi : lo;
      }
      union { unsigned u[4]; bf16x8 v; } pb;
      pb.u[0] = bu[0]; pb.u[1] = bu[1]; pb.u[2] = bu[2]; pb.u[3] = bu[3];
#pragma unroll
      for (int f = 0; f < 8; ++f) {
        bf16x8 vtf = *reinterpret_cast<const bf16x8*>(
            &VT_lds[(f * 16 + lr) * 64 + (((ks * 64 + lg * 16) ^ swz) >> 1)]);
        cacc[f] = mfma16(vtf, pb.v, cacc[f]);
      }
    }
  }

  // O^T frag: col = q = lr, row = d = f*16 + lg*4 + r  -> packed 8B stores
  if (q_idx < S_) {
    float inv = 1.f / lst;
    unsigned short* cp = ctx + ((size_t)(b * S_ + q_idx)) * D_ + hh * 128;
#pragma unroll
    for (int f = 0; f < 8; ++f) {
      unsigned lo = (unsigned)f2bf(cacc[f][0] * inv) | ((unsigned)f2bf(cacc[f][1] * inv) << 16);
      unsigned hi = (unsigned)f2bf(cacc[f][2] * inv) | ((unsigned)f2bf(cacc[f][3] * inv) << 16);
      uint2 ov; ov.x = lo; ov.y = hi;
      *reinterpret_cast<uint2*>(cp + f * 16 + lg * 4) = ov;
    }
  }
}

// ---------------- mean pool over sequence (8-way s-chunked, atomic) ----------------
__global__ __launch_bounds__(256) void meanpool(const unsigned short* __restrict__ xn,
    float* __restrict__ out) {
  int d = blockIdx.x * 256 + threadIdx.x;
  int b = blockIdx.y;
  int s0 = blockIdx.z * 125;
  const unsigned short* p = xn + ((size_t)b * S_ + s0) * D_ + d;
  float s = 0.f;
  for (int i = 0; i < 125; ++i) s += bf2f(p[(size_t)i * D_]);
  atomicAdd(&out[(size_t)b * D_ + d], s * (1.f / S_));
}

// ---------------- series branch: adds into out ----------------
__global__ __launch_bounds__(256) void series_k(const float* __restrict__ x,
    const float* __restrict__ pw, const float* __restrict__ pb, float* out) {
  __shared__ float sm[T_];
  __shared__ float emb[D_];
  __shared__ float red[4];
  int b = blockIdx.x, t = threadIdx.x;
  if (t < T_) {
    float s = 0.f;
    for (int c = 0; c < C_; ++c) s += x[((size_t)b * C_ + c) * T_ + t];
    sm[t] = s * (1.f / C_);
  }
  __syncthreads();
  float ssq = 0.f;
#pragma unroll
  for (int j = 0; j < D_ / 256; ++j) {
    int d = j * 256 + t;
    float e = pb[d];
    for (int tt = 0; tt < T_; ++tt) e += sm[tt] * pw[(size_t)d * T_ + tt];
    emb[d] = e;
    ssq += e * e;
  }
#pragma unroll
  for (int m = 1; m < 64; m <<= 1) ssq += __shfl_xor(ssq, m);
  if ((t & 63) == 0) red[t >> 6] = ssq;
  __syncthreads();
  float tot = red[0] + red[1] + red[2] + red[3];
  float inv = 1.f / fmaxf(sqrtf(tot), 1e-12f);
#pragma unroll
  for (int j = 0; j < D_ / 256; ++j) {
    int d = j * 256 + t;
    out[(size_t)b * D_ + d] += emb[d] * inv;
  }
}

extern "C" void kernel_launch(void* const* d_in, const int* in_sizes, int n_in,
                              void* d_out, int out_size, void* d_ws, size_t ws_size,
                              hipStream_t stream) {
  const float* x      = (const float*)d_in[0];
  const int*   tok    = (const int*)d_in[1];
  const float* embedw = (const float*)d_in[2];
  const int*   wq_idx = (const int*)d_in[3];
  const float* wq_sc  = (const float*)d_in[4];
  const int*   wk_idx = (const int*)d_in[5];
  const float* wk_sc  = (const float*)d_in[6];
  const int*   wv_idx = (const int*)d_in[7];
  const float* wv_sc  = (const float*)d_in[8];
  const int*   wo_idx = (const int*)d_in[9];
  const float* wo_sc  = (const float*)d_in[10];
  const int*   wg_idx = (const int*)d_in[11];
  const float* wg_sc  = (const float*)d_in[12];
  const int*   wu_idx = (const int*)d_in[13];
  const float* wu_sc  = (const float*)d_in[14];
  const int*   wd_idx = (const int*)d_in[15];
  const float* wd_sc  = (const float*)d_in[16];
  const float* ln1    = (const float*)d_in[17];
  const float* ln2    = (const float*)d_in[18];
  const float* lnf    = (const float*)d_in[19];
  const float* projw  = (const float*)d_in[20];
  const float* projb  = (const float*)d_in[21];
  float* out = (float*)d_out;
  (void)in_sizes; (void)n_in; (void)out_size; (void)ws_size;

  char* wsp = (char*)d_ws;
  size_t off = 0;
  auto alloc = [&](size_t bytes) -> void* {
    void* p = wsp + off; off += (bytes + 255) & ~(size_t)255; return p; };
  float* cosT = (float*)alloc((size_t)S_ * DH_ * 4);
  float* sinT = (float*)alloc((size_t)S_ * DH_ * 4);
  float* hbuf = (float*)alloc((size_t)M_ * D_ * 4);
  unsigned short* xn   = (unsigned short*)alloc((size_t)M_ * D_ * 2);
  unsigned short* qkv  = (unsigned short*)alloc((size_t)3 * B_ * H_ * S_ * DH_ * 2); // 49.2MB
  unsigned short* wdeq = (unsigned short*)alloc((size_t)2 * DFF_ * D_ * 2);          // 45.1MB
  unsigned short* vt   = (unsigned short*)alloc((size_t)B_ * H_ * DH_ * 1024 * 2);   // 16.8MB
  void* R = alloc((size_t)M_ * DFF_ * 2);   // 44.1MB, time-shared: dscr (fp32 M*D) / ubuf
  float* dscr = (float*)R;                  // live: O-z1 -> ln2 merge; D-z1 -> next merge
  unsigned short* ubuf = (unsigned short*)R;// live: G/U launch -> silu_mul (disjoint)
  const size_t NH = (size_t)B_ * H_ * S_ * DH_;
  unsigned short* qb = qkv, *kb = qkv + NH, *vb = qkv + 2 * NH;
  unsigned short* ctx  = xn;     // alias: xn dead during attention
  unsigned short* gbuf = qkv;    // alias: 44MB act spans qkv (49MB), dead during MLP

  hipMemsetAsync(out, 0, (size_t)B_ * D_ * 4, stream);   // meanpool accumulates
  rope_tables<<<S_, DH_, 0, stream>>>(cosT, sinT);
  embed_gather<<<M_, 256, 0, stream>>>(tok, embedw, hbuf);

  const int my = (M_ + 127) / 128;            // 32
  const dim3 gQKV((3 * D_ / 128) * my);       // 1536 blocks
  const dim3 gAtt((D_ / 128) * my, 1, 2);     // 512 x 2 (k-split) = 1024
  const dim3 gMlp((DFF_ / 128) * my, 1, 2);   // 1376 x 2 (G,U pair) = 2752
  const size_t DD = (size_t)D_ * D_;
  const size_t FD = (size_t)DFF_ * D_;

  for (int l = 0; l < L_N; ++l) {
    const int*   wqi = wq_idx + (size_t)l * DD;
    const float* wqs = wq_sc + (size_t)l * D_ * (D_ / 64);
    const int*   wki = wk_idx + (size_t)l * DD;
    const float* wks = wk_sc + (size_t)l * D_ * (D_ / 64);
    const int*   wvi = wv_idx + (size_t)l * DD;
    const float* wvs = wv_sc + (size_t)l * D_ * (D_ / 64);
    const int*   woi = wo_idx + (size_t)l * DD;
    const float* wos = wo_sc + (size_t)l * D_ * (D_ / 64);
    const int*   wgi = wg_idx + (size_t)l * FD;
    const float* wgs = wg_sc + (size_t)l * DFF_ * (D_ / 64);
    const int*   wui = wu_idx + (size_t)l * FD;
    const float* wus = wu_sc + (size_t)l * DFF_ * (D_ / 64);
    const int*   wdi = wd_idx + (size_t)l * FD;
    const float* wds = wd_sc + (size_t)l * D_ * (DFF_ / 64);

    // ln1: plain for layer 0; merged with previous D-split partial otherwise
    rmsnorm_k<<<M_, 256, 0, stream>>>(hbuf, l == 0 ? nullptr : dscr, ln1 + l * D_, xn);

    // batch 1: Q,K,V,O -> wdeq[0..4*DD)
    {
      DqBatch bt;
      bt.j[0] = { wqi, wqs, wdeq };
      bt.j[1] = { wki, wks, wdeq + DD };
      bt.j[2] = { wvi, wvs, wdeq + 2 * DD };
      bt.j[3] = { woi, wos, wdeq + 3 * DD };
      dequant_batch<<<dim3(1, D_, 4), 256, 0, stream>>>(bt, D_);
    }
    gemm_bf16<1><<<gQKV, 256, 0, stream>>>(xn, wdeq, nullptr, M_, 3 * D_, D_, 0,
                                           qkv, nullptr, nullptr);
    rope_apply<<<(B_ * H_ * S_ * 64) / 256, 256, 0, stream>>>(qb, kb, cosT, sinT);
    vtrans_k<<<dim3(16, 2, B_ * H_), 256, 0, stream>>>(vb, vt);
    attn2_k<<<dim3(B_ * H_, 8), 512, 0, stream>>>(qb, kb, vt, ctx);
    // O-GEMM k-split: z0 -> hbuf += (kt 0..15), z1 -> dscr = (kt 16..31)
    gemm_bf16<3><<<gAtt, 256, 0, stream>>>(ctx, wdeq + 3 * DD, nullptr, M_, D_, D_, 16,
                                           hbuf, nullptr, dscr);
    rmsnorm_k<<<M_, 256, 0, stream>>>(hbuf, dscr, ln2 + l * D_, xn);

    // batch 2: G,U -> wdeq[0..2*FD)
    {
      DqBatch bt;
      bt.j[0] = { wgi, wgs, wdeq };
      bt.j[1] = { wui, wus, wdeq + FD };
      bt.j[2] = bt.j[0]; bt.j[3] = bt.j[0];
      dequant_batch<<<dim3(1, DFF_, 2), 256, 0, stream>>>(bt, D_);
    }
    // G and U co-scheduled in one launch (z picks weights/output)
    gemm_bf16<0><<<gMlp, 256, 0, stream>>>(xn, wdeq, wdeq + FD, M_, DFF_, D_, 0,
                                           gbuf, ubuf, nullptr);
    silu_mul<<<(M_ * DFF_ / 8) / 256, 256, 0, stream>>>(gbuf, ubuf);

    // batch 3: D (K = DFF)
    {
      DqBatch bt;
      bt.j[0] = { wdi, wds, wdeq };
      bt.j[1] = bt.j[0]; bt.j[2] = bt.j[0]; bt.j[3] = bt.j[0];
      dequant_batch<<<dim3(3, D_, 1), 256, 0, stream>>>(bt, DFF_);
    }
    // D-GEMM k-split: z0 -> hbuf += (kt 0..42), z1 -> dscr = (kt 43..85)
    gemm_bf16<3><<<gAtt, 256, 0, stream>>>(gbuf, wdeq, nullptr, M_, D_, DFF_, 43,
                                           hbuf, nullptr, dscr);
  }

  rmsnorm_k<<<M_, 256, 0, stream>>>(hbuf, dscr, lnf, xn);
  meanpool<<<dim3(D_ / 256, B_, 8), 256, 0, stream>>>(xn, out);
  series_k<<<B_, 256, 0, stream>>>(x, projw, projb, out);
}

// Round 13
// 1274.511 us; speedup vs baseline: 1.1183x; 1.0061x over previous
//
#include <hip/hip_runtime.h>
#include <hip/hip_bf16.h>

#define L_N 2
#define D_ 2048
#define H_ 16
#define DH_ 128
#define DFF_ 5504
#define B_ 4
#define S_ 1000
#define C_ 7
#define T_ 45
#define M_ 4000   // B_*S_

typedef short bf16x8 __attribute__((ext_vector_type(8)));
typedef float f32x4 __attribute__((ext_vector_type(4)));

__constant__ float NF4_TAB[16] = {
  -1.0f, -0.6961928009986877f, -0.5250730514526367f, -0.39491748809814453f,
  -0.28444138169288635f, -0.18477343022823334f, -0.09105003625154495f, 0.0f,
  0.07958029955625534f, 0.16093020141124725f, 0.24611230194568634f,
  0.3379152417182922f, 0.44070982933044434f, 0.5626170039176941f,
  0.7229568362236023f, 1.0f };

__device__ __forceinline__ unsigned short f2bf(float f) {
  unsigned int u = __float_as_uint(f);
  u += 0x7fffu + ((u >> 16) & 1u);          // RNE
  return (unsigned short)(u >> 16);
}
__device__ __forceinline__ float bf2f(unsigned short u) {
  return __uint_as_float(((unsigned int)u) << 16);
}
__device__ __forceinline__ f32x4 zero4() { f32x4 z; z[0]=0.f; z[1]=0.f; z[2]=0.f; z[3]=0.f; return z; }
__device__ __forceinline__ f32x4 mfma16(bf16x8 a, bf16x8 b, f32x4 c) {
  return __builtin_amdgcn_mfma_f32_16x16x32_bf16(a, b, c, 0, 0, 0);
}

typedef __attribute__((address_space(3))) unsigned int lds_u32;
typedef const __attribute__((address_space(1))) unsigned int glb_u32;
__device__ __forceinline__ void gload16(const void* g, void* l) {
  __builtin_amdgcn_global_load_lds((glb_u32*)g, (lds_u32*)l, 16, 0, 0);
}

// ---------------- rope tables ----------------
__global__ void rope_tables(float* __restrict__ cosT, float* __restrict__ sinT) {
  int s = blockIdx.x, d = threadIdx.x;   // 128 threads
  int j = d & 63;
  float inv = expf(-(float)j * (9.210340371976184f / 64.f)); // 10000^(-j/64)
  float ang = (float)s * inv;
  cosT[s * DH_ + d] = cosf(ang);
  sinT[s * DH_ + d] = sinf(ang);
}

// ---------------- embedding gather ----------------
__global__ __launch_bounds__(256) void embed_gather(const int* __restrict__ tok,
    const float* __restrict__ emb, float* __restrict__ h) {
  int row = blockIdx.x;                 // 0..3999  (b*S+s)
  int tk = tok[row];
  const float4* src = reinterpret_cast<const float4*>(emb + (size_t)tk * D_);
  float4* dst = reinterpret_cast<float4*>(h + (size_t)row * D_);
  dst[threadIdx.x] = src[threadIdx.x];
  dst[threadIdx.x + 256] = src[threadIdx.x + 256];
}

// ---------------- rmsnorm (+optional k-split merge): fp32 in -> bf16 out ----------------
__global__ __launch_bounds__(256) void rmsnorm_k(float* __restrict__ h,
    const float* __restrict__ add, const float* __restrict__ w,
    unsigned short* __restrict__ out) {
  const int row = blockIdx.x, t = threadIdx.x;
  float* hp = h + (size_t)row * D_;
  float4 a = *reinterpret_cast<const float4*>(&hp[t * 8]);
  float4 b = *reinterpret_cast<const float4*>(&hp[t * 8 + 4]);
  if (add) {
    const float* ap = add + (size_t)row * D_;
    float4 da = *reinterpret_cast<const float4*>(&ap[t * 8]);
    float4 db = *reinterpret_cast<const float4*>(&ap[t * 8 + 4]);
    a.x += da.x; a.y += da.y; a.z += da.z; a.w += da.w;
    b.x += db.x; b.y += db.y; b.z += db.z; b.w += db.w;
    *reinterpret_cast<float4*>(&hp[t * 8]) = a;
    *reinterpret_cast<float4*>(&hp[t * 8 + 4]) = b;
  }
  float ss = a.x*a.x + a.y*a.y + a.z*a.z + a.w*a.w
           + b.x*b.x + b.y*b.y + b.z*b.z + b.w*b.w;
#pragma unroll
  for (int m = 1; m < 64; m <<= 1) ss += __shfl_xor(ss, m);
  __shared__ float red[4];
  if ((t & 63) == 0) red[t >> 6] = ss;
  __syncthreads();
  float tot = red[0] + red[1] + red[2] + red[3];
  float rs = rsqrtf(tot * (1.0f / D_) + 1e-5f);
  float4 wa = *reinterpret_cast<const float4*>(&w[t * 8]);
  float4 wb = *reinterpret_cast<const float4*>(&w[t * 8 + 4]);
  unsigned r0 = (unsigned)f2bf(a.x*rs*wa.x) | ((unsigned)f2bf(a.y*rs*wa.y) << 16);
  unsigned r1 = (unsigned)f2bf(a.z*rs*wa.z) | ((unsigned)f2bf(a.w*rs*wa.w) << 16);
  unsigned r2 = (unsigned)f2bf(b.x*rs*wb.x) | ((unsigned)f2bf(b.y*rs*wb.y) << 16);
  unsigned r3 = (unsigned)f2bf(b.z*rs*wb.z) | ((unsigned)f2bf(b.w*rs*wb.w) << 16);
  int4 ov; ov.x = (int)r0; ov.y = (int)r1; ov.z = (int)r2; ov.w = (int)r3;
  *reinterpret_cast<int4*>(&out[(size_t)row * D_ + t * 8]) = ov;
}

// ---------------- batched NF4 dequant: up to 4 matrices, uniform K ----------------
struct DqJob { const int* idx; const float* sc; unsigned short* out; };
struct DqBatch { DqJob j[4]; };

__global__ __launch_bounds__(256) void dequant_batch(DqBatch bt, int K) {
  __shared__ float nf4[16];
  const int t = threadIdx.x;
  if (t < 16) nf4[t] = NF4_TAB[t];
  __syncthreads();
  const DqJob jb = bt.j[blockIdx.z];
  const int row = blockIdx.y;
  const int k0 = blockIdx.x * 2048 + t * 8;
  if (k0 >= K) return;
  const size_t base = (size_t)row * K + k0;
  int4 a = *reinterpret_cast<const int4*>(&jb.idx[base]);
  int4 b = *reinterpret_cast<const int4*>(&jb.idx[base + 4]);
  float s = jb.sc[(size_t)row * (K >> 6) + (k0 >> 6)];
  unsigned r0 = (unsigned)f2bf(nf4[a.x & 15] * s) | ((unsigned)f2bf(nf4[a.y & 15] * s) << 16);
  unsigned r1 = (unsigned)f2bf(nf4[a.z & 15] * s) | ((unsigned)f2bf(nf4[a.w & 15] * s) << 16);
  unsigned r2 = (unsigned)f2bf(nf4[b.x & 15] * s) | ((unsigned)f2bf(nf4[b.y & 15] * s) << 16);
  unsigned r3 = (unsigned)f2bf(nf4[b.z & 15] * s) | ((unsigned)f2bf(nf4[b.w & 15] * s) << 16);
  int4 ov; ov.x = (int)r0; ov.y = (int)r1; ov.z = (int)r2; ov.w = (int)r3;
  *reinterpret_cast<int4*>(&jb.out[base]) = ov;
}

// ---------------- bf16 GEMM (single-buffer 2-phase, swizzled LDS) --------
// C[M][N] = A[M][K] @ W[N][K]^T
// MODE 0: out bf16 [M][N].  blockIdx.z==1 -> use Bw2/outp2 (co-scheduled G/U pair)
// MODE 1: out bf16 qkv layout [which][B][H][S][DH] (which = gn>>11)
// MODE 3: fp32 k-split: z==0 (kt in [0,ksplit)) -> outp += acc;
//                       z==1 (kt in [ksplit,kT)) -> dscr = acc
template<int MODE>
__global__ __launch_bounds__(256, 4) void gemm_bf16(
    const unsigned short* __restrict__ A,
    const unsigned short* __restrict__ Bw,
    const unsigned short* __restrict__ Bw2,
    int Mdim, int N, int K, int ksplit,
    void* outp, void* outp2, float* dscr) {
  __shared__ unsigned short A_lds[128 * 64];   // XOR-swizzled rows, 16 KiB
  __shared__ unsigned short B_lds[128 * 64];
  const int t = threadIdx.x;
  const int lane = t & 63, wid = t >> 6;
  const int z = blockIdx.z;

  const unsigned short* Bsrc = (MODE == 0 && z) ? Bw2 : Bw;
  void* osel = (MODE == 0 && z) ? outp2 : outp;

  // XCD-banded m-grouped mapping (my == 32 == 8 xcd * 4 for all launches)
  const int bid = blockIdx.x;
  const int xcd = bid & 7, l = bid >> 3;
  const int m_blk = xcd * 4 + (l & 3);
  const int n_blk = l >> 2;
  const int n0 = n_blk * 128;
  const int m0 = m_blk * 128;

  const int wm = (wid >> 1) * 64, wn = (wid & 1) * 64;
  const int lr = lane & 15, lg = lane >> 4;
  const int lrow = lane >> 3;
  const int lslot = (((lane & 7) ^ lrow) << 4);
  const int rswz = (lr & 7) << 4;

  f32x4 acc[4][4];
#pragma unroll
  for (int i = 0; i < 4; ++i)
#pragma unroll
    for (int j = 0; j < 4; ++j) acc[i][j] = zero4();

  const int kT = K >> 6;
  const int ktlo = (MODE == 3) ? (z ? ksplit : 0) : 0;
  const int kthi = (MODE == 3) ? (z ? kT : ksplit) : kT;
  const size_t rowb = (size_t)(K * 2);

  for (int kt = ktlo; kt < kthi; ++kt) {
#pragma unroll
    for (int c0 = 0; c0 < 4; ++c0) {
      const int c = wid + 4 * c0;
      int gr = m0 + c * 8 + lrow;
      gr = gr < Mdim ? gr : Mdim - 1;
      gload16((const char*)A + (size_t)gr * rowb + kt * 128 + lslot,
              (char*)&A_lds[0] + c * 1024);
      const int nr = n0 + c * 8 + lrow;
      gload16((const char*)Bsrc + (size_t)nr * rowb + kt * 128 + lslot,
              (char*)&B_lds[0] + c * 1024);
    }
    __syncthreads();
#pragma unroll
    for (int ks = 0; ks < 2; ++ks) {
      bf16x8 af[4], bfr[4];
      const int cb = (ks * 64 + lg * 16) ^ rswz;
#pragma unroll
      for (int i = 0; i < 4; ++i) {
        af[i]  = *reinterpret_cast<const bf16x8*>(
                   (const char*)&A_lds[0] + (wm + i * 16 + lr) * 128 + cb);
        bfr[i] = *reinterpret_cast<const bf16x8*>(
                   (const char*)&B_lds[0] + (wn + i * 16 + lr) * 128 + cb);
      }
      __builtin_amdgcn_s_setprio(1);
#pragma unroll
      for (int mi = 0; mi < 4; ++mi)
#pragma unroll
        for (int ni = 0; ni < 4; ++ni)
          acc[mi][ni] = mfma16(af[mi], bfr[ni], acc[mi][ni]);
      __builtin_amdgcn_s_setprio(0);
    }
    __syncthreads();
  }

#pragma unroll
  for (int mi = 0; mi < 4; ++mi) {
#pragma unroll
    for (int r = 0; r < 4; ++r) {
      int gm = m0 + wm + mi * 16 + lg * 4 + r;
      if (gm >= Mdim) continue;
#pragma unroll
      for (int ni = 0; ni < 4; ++ni) {
        int gn = n0 + wn + ni * 16 + lr;
        float v = acc[mi][ni][r];
        if (MODE == 0) {
          ((unsigned short*)osel)[(size_t)gm * N + gn] = f2bf(v);
        } else if (MODE == 1) {
          const int which = gn >> 11;
          const int hh = (gn >> 7) & 15, dd = gn & 127;
          const int b = gm / S_, s = gm - b * S_;
          ((unsigned short*)outp)[
            (((size_t)which * (B_ * H_) + b * H_ + hh) * S_ + s) * DH_ + dd] = f2bf(v);
        } else {
          if (z == 0) ((float*)outp)[(size_t)gm * N + gn] += v;
          else        dscr[(size_t)gm * N + gn] = v;
        }
      }
    }
  }
}

// ---------------- silu-mul: g = silu(g) * u (elementwise, bf16) ----------------
__global__ __launch_bounds__(256) void silu_mul(unsigned short* __restrict__ g,
    const unsigned short* __restrict__ u) {
  const size_t i = ((size_t)blockIdx.x * 256 + threadIdx.x) * 8;
  int4 gv = *reinterpret_cast<const int4*>(&g[i]);
  int4 uv = *reinterpret_cast<const int4*>(&u[i]);
  const unsigned* gp = reinterpret_cast<const unsigned*>(&gv);
  const unsigned* up = reinterpret_cast<const unsigned*>(&uv);
  unsigned ov[4];
#pragma unroll
  for (int j = 0; j < 4; ++j) {
    float g0 = bf2f(gp[j] & 0xffffu), g1 = bf2f(gp[j] >> 16);
    float u0 = bf2f(up[j] & 0xffffu), u1 = bf2f(up[j] >> 16);
    float s0 = g0 / (1.f + __expf(-g0)) * u0;
    float s1 = g1 / (1.f + __expf(-g1)) * u1;
    ov[j] = (unsigned)f2bf(s0) | ((unsigned)f2bf(s1) << 16);
  }
  int4 o; o.x = (int)ov[0]; o.y = (int)ov[1]; o.z = (int)ov[2]; o.w = (int)ov[3];
  *reinterpret_cast<int4*>(&g[i]) = o;
}

// ---------------- rope apply (in-place, q & k) — vectorized x8 ----------------
// thread handles 8 consecutive d in [0,64): 16B loads/stores on lo/hi halves.
__global__ __launch_bounds__(256) void rope_apply(unsigned short* __restrict__ qb,
    unsigned short* __restrict__ kb, const float* __restrict__ cosT,
    const float* __restrict__ sinT) {
  size_t idx = (size_t)blockIdx.x * 256 + threadIdx.x;  // B*H*S*8 slots
  const int d0 = (int)(idx & 7) << 3;
  const size_t row = idx >> 3;          // (b*H+h)*S + s
  const int s = (int)(row % S_);
  const size_t base = row * DH_;

  float4 c0 = *reinterpret_cast<const float4*>(&cosT[s * DH_ + d0]);
  float4 c1 = *reinterpret_cast<const float4*>(&cosT[s * DH_ + d0 + 4]);
  float4 s0 = *reinterpret_cast<const float4*>(&sinT[s * DH_ + d0]);
  float4 s1 = *reinterpret_cast<const float4*>(&sinT[s * DH_ + d0 + 4]);
  const float cc[8] = {c0.x, c0.y, c0.z, c0.w, c1.x, c1.y, c1.z, c1.w};
  const float ss[8] = {s0.x, s0.y, s0.z, s0.w, s1.x, s1.y, s1.z, s1.w};

#pragma unroll
  for (int which = 0; which < 2; ++which) {
    unsigned short* p = which ? kb : qb;
    int4 lo = *reinterpret_cast<const int4*>(&p[base + d0]);
    int4 hi = *reinterpret_cast<const int4*>(&p[base + d0 + 64]);
    const unsigned* lw = reinterpret_cast<const unsigned*>(&lo);
    const unsigned* hw = reinterpret_cast<const unsigned*>(&hi);
    unsigned olw[4], ohw[4];
#pragma unroll
    for (int j = 0; j < 4; ++j) {
      float l0 = bf2f((unsigned short)(lw[j] & 0xffffu));
      float l1 = bf2f((unsigned short)(lw[j] >> 16));
      float h0 = bf2f((unsigned short)(hw[j] & 0xffffu));
      float h1 = bf2f((unsigned short)(hw[j] >> 16));
      const float ca = cc[2 * j], cb2 = cc[2 * j + 1];
      const float sa = ss[2 * j], sb = ss[2 * j + 1];
      olw[j] = (unsigned)f2bf(l0 * ca - h0 * sa) | ((unsigned)f2bf(l1 * cb2 - h1 * sb) << 16);
      ohw[j] = (unsigned)f2bf(h0 * ca + l0 * sa) | ((unsigned)f2bf(h1 * cb2 + l1 * sb) << 16);
    }
    int4 olo, ohi;
    olo.x = (int)olw[0]; olo.y = (int)olw[1]; olo.z = (int)olw[2]; olo.w = (int)olw[3];
    ohi.x = (int)ohw[0]; ohi.y = (int)ohw[1]; ohi.z = (int)ohw[2]; ohi.w = (int)ohw[3];
    *reinterpret_cast<int4*>(&p[base + d0]) = olo;
    *reinterpret_cast<int4*>(&p[base + d0 + 64]) = ohi;
  }
}

// ---------------- V transpose: vb [b][h][s][128] -> vt [bh][128][1024] ----------------
__global__ __launch_bounds__(256) void vtrans_k(const unsigned short* __restrict__ vb,
    unsigned short* __restrict__ vt) {
  __shared__ unsigned int tile[64][33];
  const int t = threadIdx.x;
  const int s0 = blockIdx.x * 64, d0 = blockIdx.y * 64, bh = blockIdx.z;
#pragma unroll
  for (int j = 0; j < 2; ++j) {
    int idx = t + 256 * j;
    int s_r = idx >> 3, c8 = (idx & 7) << 3;
    int srow = s0 + s_r; srow = srow < S_ ? srow : S_ - 1;
    int4 v = *reinterpret_cast<const int4*>(&vb[((size_t)bh * S_ + srow) * DH_ + d0 + c8]);
    tile[s_r][(c8 >> 1) + 0] = (unsigned)v.x;
    tile[s_r][(c8 >> 1) + 1] = (unsigned)v.y;
    tile[s_r][(c8 >> 1) + 2] = (unsigned)v.z;
    tile[s_r][(c8 >> 1) + 3] = (unsigned)v.w;
  }
  __syncthreads();
#pragma unroll
  for (int j = 0; j < 2; ++j) {
    int idx = t + 256 * j;
    int d_r = idx >> 3, s8 = (idx & 7) << 3;
    unsigned r[8];
#pragma unroll
    for (int e = 0; e < 8; ++e) {
      unsigned wv = tile[s8 + e][d_r >> 1];
      r[e] = (d_r & 1) ? (wv >> 16) : (wv & 0xffffu);
    }
    int4 ov;
    ov.x = (int)(r[0] | (r[1] << 16));
    ov.y = (int)(r[2] | (r[3] << 16));
    ov.z = (int)(r[4] | (r[5] << 16));
    ov.w = (int)(r[6] | (r[7] << 16));
    *reinterpret_cast<int4*>(&vt[((size_t)(bh * 128 + d0 + d_r)) * 1024 + s0 + s8]) = ov;
  }
}

// ---------------- causal flash attention v2 (swapped-QK, 8 waves, 128 q rows) --------
__global__ __launch_bounds__(512, 4) void attn2_k(const unsigned short* __restrict__ qg,
    const unsigned short* __restrict__ kg, const unsigned short* __restrict__ vtg,
    unsigned short* __restrict__ ctx) {
  __shared__ unsigned short K_lds[64 * 128];
  __shared__ unsigned short VT_lds[128 * 64];
  const int t = threadIdx.x, lane = t & 63, w = t >> 6;
  const int lr = lane & 15, lg = lane >> 4;
  const int bh = blockIdx.x, qt = blockIdx.y;
  const int q0 = qt * 128;
  const int b = bh >> 4, hh = bh & 15;
  const size_t kbase2 = (size_t)bh * S_ * DH_ * 2;   // byte base of this head
  const int q_idx = q0 + w * 16 + lr;
  const int swz = (lr & 7) << 4;

  bf16x8 qf[4];
#pragma unroll
  for (int ks = 0; ks < 4; ++ks) {
    bf16x8 z;
#pragma unroll
    for (int e = 0; e < 8; ++e) z[e] = 0;
    if (q_idx < S_)
      z = *reinterpret_cast<const bf16x8*>(
            (const char*)qg + kbase2 + (size_t)q_idx * 256 + ks * 64 + lg * 16);
    qf[ks] = z;
  }
  float mst = -1e30f, lst = 0.f;
  f32x4 cacc[8];
#pragma unroll
  for (int f = 0; f < 8; ++f) cacc[f] = zero4();

  const int q_hi = (q0 + 127 < S_) ? q0 + 127 : S_ - 1;
  const int nt = q_hi / 64 + 1;
  const int wq_max = q0 + w * 16 + 15;

  for (int kt = 0; kt < nt; ++kt) {
    const int kv0 = kt * 64;
    __syncthreads();
    // stage K [64][128] and VT [128][64], XOR-swizzled source -> linear LDS
#pragma unroll
    for (int j = 0; j < 2; ++j) {
      const int chunk = w + 8 * j;            // 0..15, 1024B each
      int krow = chunk * 4 + (lane >> 4);     // 4 rows x 256B
      int kcolb = (lane & 15) << 4;
      int gr = kv0 + krow; gr = gr < S_ ? gr : S_ - 1;
      gload16((const char*)kg + kbase2 + (size_t)gr * 256 + (kcolb ^ ((krow & 7) << 4)),
              (char*)K_lds + chunk * 1024);
      int vrow = chunk * 8 + (lane >> 3);     // 8 rows x 128B
      int vcolb = (lane & 7) << 4;
      gload16((const char*)vtg + ((size_t)(bh * 128 + vrow) * 1024 + kv0) * 2 + (vcolb ^ ((vrow & 7) << 4)),
              (char*)VT_lds + chunk * 1024);
    }
    __syncthreads();
    if (kv0 > wq_max) continue;               // whole wave masked this tile

    // S^T = K . Q^T  (row = kv, col = q = lr)
    f32x4 sacc[4];
#pragma unroll
    for (int c = 0; c < 4; ++c) sacc[c] = zero4();
#pragma unroll
    for (int ks = 0; ks < 4; ++ks) {
#pragma unroll
      for (int c = 0; c < 4; ++c) {
        bf16x8 kf = *reinterpret_cast<const bf16x8*>(
            &K_lds[(c * 16 + lr) * 128 + (((ks * 64 + lg * 16) ^ swz) >> 1)]);
        sacc[c] = mfma16(kf, qf[ks], sacc[c]);
      }
    }
    // mask + online softmax (per-lane scalar m/l; reduce across lg groups)
    float p[4][4];
    float mx = -1e30f;
#pragma unroll
    for (int c = 0; c < 4; ++c)
#pragma unroll
      for (int r = 0; r < 4; ++r) {
        int kv = kv0 + c * 16 + lg * 4 + r;
        float v = sacc[c][r] * 0.08838834764831845f;   // 1/sqrt(128)
        if (kv > q_idx || kv >= S_) v = -1e30f;
        p[c][r] = v;
        mx = fmaxf(mx, v);
      }
    mx = fmaxf(mx, __shfl_xor(mx, 16));
    mx = fmaxf(mx, __shfl_xor(mx, 32));
    float mn = fmaxf(mst, mx);
    float corr = __expf(mst - mn);
    mst = mn;
    float rs = 0.f;
#pragma unroll
    for (int c = 0; c < 4; ++c)
#pragma unroll
      for (int r = 0; r < 4; ++r) {
        float e = __expf(p[c][r] - mn);
        p[c][r] = e;
        rs += e;
      }
    rs += __shfl_xor(rs, 16);
    rs += __shfl_xor(rs, 32);
    lst = lst * corr + rs;
#pragma unroll
    for (int f = 0; f < 8; ++f)
#pragma unroll
      for (int r = 0; r < 4; ++r) cacc[f][r] *= corr;

    // pack P (bf16 pairs) and redistribute to PV B-operand via shfl
    unsigned pk01[4], pk23[4];
#pragma unroll
    for (int c = 0; c < 4; ++c) {
      pk01[c] = (unsigned)f2bf(p[c][0]) | ((unsigned)f2bf(p[c][1]) << 16);
      pk23[c] = (unsigned)f2bf(p[c][2]) | ((unsigned)f2bf(p[c][3]) << 16);
    }
#pragma unroll
    for (int ks = 0; ks < 2; ++ks) {
      unsigned bu[4];
#pragma unroll
      for (int jj = 0; jj < 4; ++jj) {
        const int srcl = ((lg & 1) * 2 + (jj >> 1)) * 16 + lr;
        unsigned lo = (unsigned)__shfl((int)((jj & 1) ? pk23[2 * ks]     : pk01[2 * ks]),     srcl);
        unsigned hi = (unsigned)__shfl((int)((jj & 1) ? pk23[2 * ks + 1] : pk01[2 * ks + 1]), srcl);
        bu[jj] = (lg >= 2) ? hi : lo;
      }
      union { unsigned u[4]; bf16x8 v; } pb;
      pb.u[0] = bu[0]; pb.u[1] = bu[1]; pb.u[2] = bu[2]; pb.u[3] = bu[3];
#pragma unroll
      for (int f = 0; f < 8; ++f) {
        bf16x8 vtf = *reinterpret_cast<const bf16x8*>(
            &VT_lds[(f * 16 + lr) * 64 + (((ks * 64 + lg * 16) ^ swz) >> 1)]);
        cacc[f] = mfma16(vtf, pb.v, cacc[f]);
      }
    }
  }

  // O^T frag: col = q = lr, row = d = f*16 + lg*4 + r  -> packed 8B stores
  if (q_idx < S_) {
    float inv = 1.f / lst;
    unsigned short* cp = ctx + ((size_t)(b * S_ + q_idx)) * D_ + hh * 128;
#pragma unroll
    for (int f = 0; f < 8; ++f) {
      unsigned lo = (unsigned)f2bf(cacc[f][0] * inv) | ((unsigned)f2bf(cacc[f][1] * inv) << 16);
      unsigned hi = (unsigned)f2bf(cacc[f][2] * inv) | ((unsigned)f2bf(cacc[f][3] * inv) << 16);
      uint2 ov; ov.x = lo; ov.y = hi;
      *reinterpret_cast<uint2*>(cp + f * 16 + lg * 4) = ov;
    }
  }
}

// ---------------- mean pool over sequence (8-way s-chunked, atomic) ----------------
__global__ __launch_bounds__(256) void meanpool(const unsigned short* __restrict__ xn,
    float* __restrict__ out) {
  int d = blockIdx.x * 256 + threadIdx.x;
  int b = blockIdx.y;
  int s0 = blockIdx.z * 125;
  const unsigned short* p = xn + ((size_t)b * S_ + s0) * D_ + d;
  float s = 0.f;
  for (int i = 0; i < 125; ++i) s += bf2f(p[(size_t)i * D_]);
  atomicAdd(&out[(size_t)b * D_ + d], s * (1.f / S_));
}

// ---------------- series branch: adds into out ----------------
__global__ __launch_bounds__(256) void series_k(const float* __restrict__ x,
    const float* __restrict__ pw, const float* __restrict__ pb, float* out) {
  __shared__ float sm[T_];
  __shared__ float emb[D_];
  __shared__ float red[4];
  int b = blockIdx.x, t = threadIdx.x;
  if (t < T_) {
    float s = 0.f;
    for (int c = 0; c < C_; ++c) s += x[((size_t)b * C_ + c) * T_ + t];
    sm[t] = s * (1.f / C_);
  }
  __syncthreads();
  float ssq = 0.f;
#pragma unroll
  for (int j = 0; j < D_ / 256; ++j) {
    int d = j * 256 + t;
    float e = pb[d];
    for (int tt = 0; tt < T_; ++tt) e += sm[tt] * pw[(size_t)d * T_ + tt];
    emb[d] = e;
    ssq += e * e;
  }
#pragma unroll
  for (int m = 1; m < 64; m <<= 1) ssq += __shfl_xor(ssq, m);
  if ((t & 63) == 0) red[t >> 6] = ssq;
  __syncthreads();
  float tot = red[0] + red[1] + red[2] + red[3];
  float inv = 1.f / fmaxf(sqrtf(tot), 1e-12f);
#pragma unroll
  for (int j = 0; j < D_ / 256; ++j) {
    int d = j * 256 + t;
    out[(size_t)b * D_ + d] += emb[d] * inv;
  }
}

extern "C" void kernel_launch(void* const* d_in, const int* in_sizes, int n_in,
                              void* d_out, int out_size, void* d_ws, size_t ws_size,
                              hipStream_t stream) {
  const float* x      = (const float*)d_in[0];
  const int*   tok    = (const int*)d_in[1];
  const float* embedw = (const float*)d_in[2];
  const int*   wq_idx = (const int*)d_in[3];
  const float* wq_sc  = (const float*)d_in[4];
  const int*   wk_idx = (const int*)d_in[5];
  const float* wk_sc  = (const float*)d_in[6];
  const int*   wv_idx = (const int*)d_in[7];
  const float* wv_sc  = (const float*)d_in[8];
  const int*   wo_idx = (const int*)d_in[9];
  const float* wo_sc  = (const float*)d_in[10];
  const int*   wg_idx = (const int*)d_in[11];
  const float* wg_sc  = (const float*)d_in[12];
  const int*   wu_idx = (const int*)d_in[13];
  const float* wu_sc  = (const float*)d_in[14];
  const int*   wd_idx = (const int*)d_in[15];
  const float* wd_sc  = (const float*)d_in[16];
  const float* ln1    = (const float*)d_in[17];
  const float* ln2    = (const float*)d_in[18];
  const float* lnf    = (const float*)d_in[19];
  const float* projw  = (const float*)d_in[20];
  const float* projb  = (const float*)d_in[21];
  float* out = (float*)d_out;
  (void)in_sizes; (void)n_in; (void)out_size; (void)ws_size;

  char* wsp = (char*)d_ws;
  size_t off = 0;
  auto alloc = [&](size_t bytes) -> void* {
    void* p = wsp + off; off += (bytes + 255) & ~(size_t)255; return p; };
  float* cosT = (float*)alloc((size_t)S_ * DH_ * 4);
  float* sinT = (float*)alloc((size_t)S_ * DH_ * 4);
  float* hbuf = (float*)alloc((size_t)M_ * D_ * 4);
  unsigned short* xn   = (unsigned short*)alloc((size_t)M_ * D_ * 2);
  unsigned short* qkv  = (unsigned short*)alloc((size_t)3 * B_ * H_ * S_ * DH_ * 2); // 49.2MB
  unsigned short* wdeq = (unsigned short*)alloc((size_t)2 * DFF_ * D_ * 2);          // 45.1MB
  unsigned short* vt   = (unsigned short*)alloc((size_t)B_ * H_ * DH_ * 1024 * 2);   // 16.8MB
  void* R = alloc((size_t)M_ * DFF_ * 2);   // 44.1MB, time-shared: dscr (fp32 M*D) / ubuf
  float* dscr = (float*)R;                  // live: O-z1 -> ln2 merge; D-z1 -> next merge
  unsigned short* ubuf = (unsigned short*)R;// live: G/U launch -> silu_mul (disjoint)
  const size_t NH = (size_t)B_ * H_ * S_ * DH_;
  unsigned short* qb = qkv, *kb = qkv + NH, *vb = qkv + 2 * NH;
  unsigned short* ctx  = xn;     // alias: xn dead during attention
  unsigned short* gbuf = qkv;    // alias: 44MB act spans qkv (49MB), dead during MLP

  hipMemsetAsync(out, 0, (size_t)B_ * D_ * 4, stream);   // meanpool accumulates
  rope_tables<<<S_, DH_, 0, stream>>>(cosT, sinT);
  embed_gather<<<M_, 256, 0, stream>>>(tok, embedw, hbuf);

  const int my = (M_ + 127) / 128;            // 32
  const dim3 gQKV((3 * D_ / 128) * my);       // 1536 blocks
  const dim3 gAtt((D_ / 128) * my, 1, 2);     // 512 x 2 (k-split) = 1024
  const dim3 gMlp((DFF_ / 128) * my, 1, 2);   // 1376 x 2 (G,U pair) = 2752
  const size_t DD = (size_t)D_ * D_;
  const size_t FD = (size_t)DFF_ * D_;

  for (int l = 0; l < L_N; ++l) {
    const int*   wqi = wq_idx + (size_t)l * DD;
    const float* wqs = wq_sc + (size_t)l * D_ * (D_ / 64);
    const int*   wki = wk_idx + (size_t)l * DD;
    const float* wks = wk_sc + (size_t)l * D_ * (D_ / 64);
    const int*   wvi = wv_idx + (size_t)l * DD;
    const float* wvs = wv_sc + (size_t)l * D_ * (D_ / 64);
    const int*   woi = wo_idx + (size_t)l * DD;
    const float* wos = wo_sc + (size_t)l * D_ * (D_ / 64);
    const int*   wgi = wg_idx + (size_t)l * FD;
    const float* wgs = wg_sc + (size_t)l * DFF_ * (D_ / 64);
    const int*   wui = wu_idx + (size_t)l * FD;
    const float* wus = wu_sc + (size_t)l * DFF_ * (D_ / 64);
    const int*   wdi = wd_idx + (size_t)l * FD;
    const float* wds = wd_sc + (size_t)l * D_ * (DFF_ / 64);

    // ln1: plain for layer 0; merged with previous D-split partial otherwise
    rmsnorm_k<<<M_, 256, 0, stream>>>(hbuf, l == 0 ? nullptr : dscr, ln1 + l * D_, xn);

    // batch 1: Q,K,V,O -> wdeq[0..4*DD)
    {
      DqBatch bt;
      bt.j[0] = { wqi, wqs, wdeq };
      bt.j[1] = { wki, wks, wdeq + DD };
      bt.j[2] = { wvi, wvs, wdeq + 2 * DD };
      bt.j[3] = { woi, wos, wdeq + 3 * DD };
      dequant_batch<<<dim3(1, D_, 4), 256, 0, stream>>>(bt, D_);
    }
    gemm_bf16<1><<<gQKV, 256, 0, stream>>>(xn, wdeq, nullptr, M_, 3 * D_, D_, 0,
                                           qkv, nullptr, nullptr);
    rope_apply<<<(B_ * H_ * S_ * 8) / 256, 256, 0, stream>>>(qb, kb, cosT, sinT);
    vtrans_k<<<dim3(16, 2, B_ * H_), 256, 0, stream>>>(vb, vt);
    attn2_k<<<dim3(B_ * H_, 8), 512, 0, stream>>>(qb, kb, vt, ctx);
    // O-GEMM k-split: z0 -> hbuf += (kt 0..15), z1 -> dscr = (kt 16..31)
    gemm_bf16<3><<<gAtt, 256, 0, stream>>>(ctx, wdeq + 3 * DD, nullptr, M_, D_, D_, 16,
                                           hbuf, nullptr, dscr);
    rmsnorm_k<<<M_, 256, 0, stream>>>(hbuf, dscr, ln2 + l * D_, xn);

    // batch 2: G,U -> wdeq[0..2*FD)
    {
      DqBatch bt;
      bt.j[0] = { wgi, wgs, wdeq };
      bt.j[1] = { wui, wus, wdeq + FD };
      bt.j[2] = bt.j[0]; bt.j[3] = bt.j[0];
      dequant_batch<<<dim3(1, DFF_, 2), 256, 0, stream>>>(bt, D_);
    }
    // G and U co-scheduled in one launch (z picks weights/output)
    gemm_bf16<0><<<gMlp, 256, 0, stream>>>(xn, wdeq, wdeq + FD, M_, DFF_, D_, 0,
                                           gbuf, ubuf, nullptr);
    silu_mul<<<(M_ * DFF_ / 8) / 256, 256, 0, stream>>>(gbuf, ubuf);

    // batch 3: D (K = DFF)
    {
      DqBatch bt;
      bt.j[0] = { wdi, wds, wdeq };
      bt.j[1] = bt.j[0]; bt.j[2] = bt.j[0]; bt.j[3] = bt.j[0];
      dequant_batch<<<dim3(3, D_, 1), 256, 0, stream>>>(bt, DFF_);
    }
    // D-GEMM k-split: z0 -> hbuf += (kt 0..42), z1 -> dscr = (kt 43..85)
    gemm_bf16<3><<<gAtt, 256, 0, stream>>>(gbuf, wdeq, nullptr, M_, D_, DFF_, 43,
                                           hbuf, nullptr, dscr);
  }

  rmsnorm_k<<<M_, 256, 0, stream>>>(hbuf, dscr, lnf, xn);
  meanpool<<<dim3(D_ / 256, B_, 8), 256, 0, stream>>>(xn, out);
  series_k<<<B_, 256, 0, stream>>>(x, projw, projb, out);
}